// Round 1
// baseline (2814.218 us; speedup 1.0000x reference)
//
#include <hip/hip_runtime.h>
#include <hip/hip_bf16.h>
#include <math.h>

// Problem constants (match reference)
#define N_NODES 50000
#define N_EDGES 800000
#define DIM 64
#define NEG_SLOPE 0.2f
#define EPS 1e-5f

// Per-thread-row LDS staging: thread t owns row buf[t*65 .. t*65+63].
// Stride 65 dwords -> bank (65*t + k) % 32 = (t + k) % 32 -> conflict-free
// per-k broadcast-style reads (all lanes distinct banks).
#define ROWS 65

__device__ __forceinline__ float lrelu(float v) {
    // x>=0 -> x ; x<0 -> 0.2x  ==  max(x, 0.2x)
    return fmaxf(v, NEG_SLOPE * v);
}

// ---------------------------------------------------------------------------
// Node pooling: Vp = lrelu(lrelu(V) @ pAw + pAb) @ pBw + pBb
// ---------------------------------------------------------------------------
__global__ __launch_bounds__(128) void node_kernel(
    const float* __restrict__ V,
    const float* __restrict__ pAw, const float* __restrict__ pAb,
    const float* __restrict__ pBw, const float* __restrict__ pBb,
    float* __restrict__ Vp)
{
    __shared__ float buf[128 * ROWS];
    const int tid = threadIdx.x;
    const size_t n = (size_t)blockIdx.x * 128 + tid;
    if (n >= N_NODES) return;

    float* myrow = &buf[tid * ROWS];
    const float4* Vr = (const float4*)(V + n * DIM);
#pragma unroll
    for (int i = 0; i < 16; ++i) {
        float4 v = Vr[i];
        myrow[4*i+0] = lrelu(v.x);
        myrow[4*i+1] = lrelu(v.y);
        myrow[4*i+2] = lrelu(v.z);
        myrow[4*i+3] = lrelu(v.w);
    }

    float x[DIM];
    // layer A
#pragma unroll
    for (int j = 0; j < DIM; ++j) x[j] = pAb[j];
    for (int k = 0; k < DIM; ++k) {
        const float a = myrow[k];
        const float* w = &pAw[k * DIM];
#pragma unroll
        for (int j = 0; j < DIM; ++j) x[j] = fmaf(a, w[j], x[j]);
    }
#pragma unroll
    for (int j = 0; j < DIM; ++j) myrow[j] = lrelu(x[j]);

    // layer B
#pragma unroll
    for (int j = 0; j < DIM; ++j) x[j] = pBb[j];
    for (int k = 0; k < DIM; ++k) {
        const float a = myrow[k];
        const float* w = &pBw[k * DIM];
#pragma unroll
        for (int j = 0; j < DIM; ++j) x[j] = fmaf(a, w[j], x[j]);
    }

    float4* Od = (float4*)(Vp + n * DIM);
#pragma unroll
    for (int i = 0; i < 16; ++i) {
        float4 v;
        v.x = x[4*i+0]; v.y = x[4*i+1]; v.z = x[4*i+2]; v.w = x[4*i+3];
        Od[i] = v;
    }
}

// ---------------------------------------------------------------------------
// Fused edge pipeline:
//   x1 = relu(E@w1+b1); x2 = relu(x1@w2+b2)
//   scale = sigmoid(x2@Bw+Bb); shift = x2@Cw+Cb
//   msg = scale * Vp[src] + shift; M = max(msg,EPS)^2
//   atomicAdd into ssum[dst], cnt[dst]
// ---------------------------------------------------------------------------
__global__ __launch_bounds__(128) void edge_kernel(
    const float* __restrict__ E,
    const int* __restrict__ src, const int* __restrict__ dst,
    const float* __restrict__ w1, const float* __restrict__ b1,
    const float* __restrict__ w2, const float* __restrict__ b2,
    const float* __restrict__ Bw, const float* __restrict__ Bb,
    const float* __restrict__ Cw, const float* __restrict__ Cb,
    const float* __restrict__ Vp,
    float* __restrict__ ssum, float* __restrict__ cnt)
{
    __shared__ float buf[128 * ROWS];
    const int tid = threadIdx.x;
    const size_t e = (size_t)blockIdx.x * 128 + tid;   // 800000 % 128 == 0, no guard

    float* myrow = &buf[tid * ROWS];
    const float4* Er = (const float4*)(E + e * DIM);
#pragma unroll
    for (int i = 0; i < 16; ++i) {
        float4 v = Er[i];
        myrow[4*i+0] = v.x; myrow[4*i+1] = v.y;
        myrow[4*i+2] = v.z; myrow[4*i+3] = v.w;
    }

    float x[DIM];

    // ---- layer 1: relu(E@w1+b1) ----
#pragma unroll
    for (int j = 0; j < DIM; ++j) x[j] = b1[j];
    for (int k = 0; k < DIM; ++k) {
        const float a = myrow[k];
        const float* w = &w1[k * DIM];
#pragma unroll
        for (int j = 0; j < DIM; ++j) x[j] = fmaf(a, w[j], x[j]);
    }
#pragma unroll
    for (int j = 0; j < DIM; ++j) myrow[j] = fmaxf(x[j], 0.f);

    // ---- layer 2: relu(x1@w2+b2) ----
#pragma unroll
    for (int j = 0; j < DIM; ++j) x[j] = b2[j];
    for (int k = 0; k < DIM; ++k) {
        const float a = myrow[k];
        const float* w = &w2[k * DIM];
#pragma unroll
        for (int j = 0; j < DIM; ++j) x[j] = fmaf(a, w[j], x[j]);
    }
#pragma unroll
    for (int j = 0; j < DIM; ++j) myrow[j] = fmaxf(x[j], 0.f);

    // ---- gate: scale = sigmoid(x2@Bw+Bb) ----
#pragma unroll
    for (int j = 0; j < DIM; ++j) x[j] = Bb[j];
    for (int k = 0; k < DIM; ++k) {
        const float a = myrow[k];
        const float* w = &Bw[k * DIM];
#pragma unroll
        for (int j = 0; j < DIM; ++j) x[j] = fmaf(a, w[j], x[j]);
    }
    float scale[DIM];
#pragma unroll
    for (int j = 0; j < DIM; ++j) scale[j] = 1.f / (1.f + __expf(-x[j]));

    // ---- shift: x2@Cw+Cb ----
#pragma unroll
    for (int j = 0; j < DIM; ++j) x[j] = Cb[j];
    for (int k = 0; k < DIM; ++k) {
        const float a = myrow[k];
        const float* w = &Cw[k * DIM];
#pragma unroll
        for (int j = 0; j < DIM; ++j) x[j] = fmaf(a, w[j], x[j]);
    }

    // ---- gather, message, scatter-add ----
    const int s = src[e];
    const int d = dst[e];
    const float4* Vr = (const float4*)(Vp + (size_t)s * DIM);
    float* srow = ssum + (size_t)d * DIM;
#pragma unroll
    for (int i = 0; i < 16; ++i) {
        float4 v = Vr[i];
        float m;
        m = fmaf(scale[4*i+0], v.x, x[4*i+0]); m = fmaxf(m, EPS); atomicAdd(&srow[4*i+0], m*m);
        m = fmaf(scale[4*i+1], v.y, x[4*i+1]); m = fmaxf(m, EPS); atomicAdd(&srow[4*i+1], m*m);
        m = fmaf(scale[4*i+2], v.z, x[4*i+2]); m = fmaxf(m, EPS); atomicAdd(&srow[4*i+2], m*m);
        m = fmaf(scale[4*i+3], v.w, x[4*i+3]); m = fmaxf(m, EPS); atomicAdd(&srow[4*i+3], m*m);
    }
    atomicAdd(&cnt[d], 1.0f);
}

// ---------------------------------------------------------------------------
// Finalize: out = sqrt(ssum / max(cnt,1)) in-place on d_out
// ---------------------------------------------------------------------------
__global__ __launch_bounds__(256) void finalize_kernel(
    float* __restrict__ out, const float* __restrict__ cnt)
{
    const size_t i = (size_t)blockIdx.x * 256 + threadIdx.x;  // float4 index
    if (i >= (size_t)N_NODES * DIM / 4) return;
    const float c = fmaxf(cnt[i >> 4], 1.0f);   // 16 float4 per node
    const float rc = 1.0f / c;
    float4* p = ((float4*)out) + i;
    float4 v = *p;
    v.x = sqrtf(v.x * rc);
    v.y = sqrtf(v.y * rc);
    v.z = sqrtf(v.z * rc);
    v.w = sqrtf(v.w * rc);
    *p = v;
}

extern "C" void kernel_launch(void* const* d_in, const int* in_sizes, int n_in,
                              void* d_out, int out_size, void* d_ws, size_t ws_size,
                              hipStream_t stream) {
    const float* V   = (const float*)d_in[0];
    const float* E   = (const float*)d_in[1];
    const int*   src = (const int*)d_in[2];
    const int*   dst = (const int*)d_in[3];
    const float* w1  = (const float*)d_in[4];
    const float* b1  = (const float*)d_in[5];
    const float* w2  = (const float*)d_in[6];
    const float* b2  = (const float*)d_in[7];
    const float* Bw  = (const float*)d_in[8];
    const float* Bb  = (const float*)d_in[9];
    const float* Cw  = (const float*)d_in[10];
    const float* Cb  = (const float*)d_in[11];
    const float* pAw = (const float*)d_in[12];
    const float* pAb = (const float*)d_in[13];
    const float* pBw = (const float*)d_in[14];
    const float* pBb = (const float*)d_in[15];

    float* out = (float*)d_out;                       // used as ssum accumulator, finalized in-place
    float* Vp  = (float*)d_ws;                        // [N_NODES * DIM]
    float* cnt = (float*)((char*)d_ws + (size_t)N_NODES * DIM * sizeof(float)); // [N_NODES]

    // zero accumulators every call (graph-capture-safe, deterministic replays)
    hipMemsetAsync(d_out, 0, (size_t)N_NODES * DIM * sizeof(float), stream);
    hipMemsetAsync(cnt, 0, (size_t)N_NODES * sizeof(float), stream);

    node_kernel<<<(N_NODES + 127) / 128, 128, 0, stream>>>(V, pAw, pAb, pBw, pBb, Vp);
    edge_kernel<<<N_EDGES / 128, 128, 0, stream>>>(E, src, dst, w1, b1, w2, b2,
                                                   Bw, Bb, Cw, Cb, Vp, out, cnt);
    finalize_kernel<<<(N_NODES * DIM / 4 + 255) / 256, 256, 0, stream>>>(out, cnt);
}

// Round 2
// 888.726 us; speedup vs baseline: 3.1666x; 3.1666x over previous
//
#include <hip/hip_runtime.h>
#include <hip/hip_bf16.h>
#include <math.h>

// Problem constants (match reference)
#define N_NODES 50000
#define N_EDGES 800000
#define DIM 64
#define NEG_SLOPE 0.2f
#define EPS 1e-5f

// Per-thread-row LDS staging: thread t owns row buf[t*65 .. t*65+63].
// Stride 65 dwords -> bank (65*t + k) % 32 = (t + k) % 32 -> 2 lanes/bank
// per-k reads (free per m136).
#define ROWS 65

__device__ __forceinline__ float lrelu(float v) {
    return fmaxf(v, NEG_SLOPE * v);
}

__device__ __forceinline__ unsigned pack2bf(float a, float b) {
    unsigned short lo = __bfloat16_as_ushort(__float2bfloat16(a));
    unsigned short hi = __bfloat16_as_ushort(__float2bfloat16(b));
    return (unsigned)lo | ((unsigned)hi << 16);
}

// ---------------------------------------------------------------------------
// Node pooling: Vp = lrelu(lrelu(V) @ pAw + pAb) @ pBw + pBb
// ---------------------------------------------------------------------------
__global__ __launch_bounds__(128) void node_kernel(
    const float* __restrict__ V,
    const float* __restrict__ pAw, const float* __restrict__ pAb,
    const float* __restrict__ pBw, const float* __restrict__ pBb,
    float* __restrict__ Vp)
{
    __shared__ float buf[128 * ROWS];
    const int tid = threadIdx.x;
    const size_t n = (size_t)blockIdx.x * 128 + tid;
    if (n >= N_NODES) return;

    float* myrow = &buf[tid * ROWS];
    const float4* Vr = (const float4*)(V + n * DIM);
#pragma unroll
    for (int i = 0; i < 16; ++i) {
        float4 v = Vr[i];
        myrow[4*i+0] = lrelu(v.x);
        myrow[4*i+1] = lrelu(v.y);
        myrow[4*i+2] = lrelu(v.z);
        myrow[4*i+3] = lrelu(v.w);
    }

    float x[DIM];
#pragma unroll
    for (int j = 0; j < DIM; ++j) x[j] = pAb[j];
    for (int k = 0; k < DIM; ++k) {
        const float a = myrow[k];
        const float* w = &pAw[k * DIM];
#pragma unroll
        for (int j = 0; j < DIM; ++j) x[j] = fmaf(a, w[j], x[j]);
    }
#pragma unroll
    for (int j = 0; j < DIM; ++j) myrow[j] = lrelu(x[j]);

#pragma unroll
    for (int j = 0; j < DIM; ++j) x[j] = pBb[j];
    for (int k = 0; k < DIM; ++k) {
        const float a = myrow[k];
        const float* w = &pBw[k * DIM];
#pragma unroll
        for (int j = 0; j < DIM; ++j) x[j] = fmaf(a, w[j], x[j]);
    }

    float4* Od = (float4*)(Vp + n * DIM);
#pragma unroll
    for (int i = 0; i < 16; ++i) {
        float4 v;
        v.x = x[4*i+0]; v.y = x[4*i+1]; v.z = x[4*i+2]; v.w = x[4*i+3];
        Od[i] = v;
    }
}

// ---------------------------------------------------------------------------
// CSR build: histogram -> single-block scan -> scatter edge ids
// ---------------------------------------------------------------------------
__global__ __launch_bounds__(256) void hist_kernel(
    const int* __restrict__ dst, int* __restrict__ cnt)
{
    const int e = blockIdx.x * 256 + threadIdx.x;   // 800000 % 256 == 0
    atomicAdd(&cnt[dst[e]], 1);
}

#define SCAN_T 1024
#define SCAN_C 49   // 1024*49 = 50176 >= 50000
__global__ __launch_bounds__(SCAN_T) void scan_kernel(
    const int* __restrict__ cnt, int* __restrict__ offs, int* __restrict__ cursor)
{
    __shared__ int ts[SCAN_T];
    const int t = threadIdx.x;
    const int base = t * SCAN_C;
    int s = 0;
    for (int i = 0; i < SCAN_C; ++i) {
        const int idx = base + i;
        s += (idx < N_NODES) ? cnt[idx] : 0;
    }
    ts[t] = s;
    __syncthreads();
    // inclusive Hillis-Steele block scan
    for (int off = 1; off < SCAN_T; off <<= 1) {
        const int add = (t >= off) ? ts[t - off] : 0;
        __syncthreads();
        ts[t] += add;
        __syncthreads();
    }
    int run = (t == 0) ? 0 : ts[t - 1];
    for (int i = 0; i < SCAN_C; ++i) {
        const int idx = base + i;
        if (idx < N_NODES) {
            offs[idx] = run;
            cursor[idx] = run;
            run += cnt[idx];
        }
    }
}

__global__ __launch_bounds__(256) void scatter_kernel(
    const int* __restrict__ dst, int* __restrict__ cursor, int* __restrict__ eidx)
{
    const int e = blockIdx.x * 256 + threadIdx.x;
    const int pos = atomicAdd(&cursor[dst[e]], 1);
    eidx[pos] = e;
}

// ---------------------------------------------------------------------------
// Fused edge pipeline; writes M = max(msg,EPS)^2 as packed bf16, NO atomics.
// ---------------------------------------------------------------------------
__global__ __launch_bounds__(128) void edge_kernel(
    const float* __restrict__ E,
    const int* __restrict__ src,
    const float* __restrict__ w1, const float* __restrict__ b1,
    const float* __restrict__ w2, const float* __restrict__ b2,
    const float* __restrict__ Bw, const float* __restrict__ Bb,
    const float* __restrict__ Cw, const float* __restrict__ Cb,
    const float* __restrict__ Vp,
    __hip_bfloat16* __restrict__ msg)
{
    __shared__ float buf[128 * ROWS];
    const int tid = threadIdx.x;
    const size_t e = (size_t)blockIdx.x * 128 + tid;   // 800000 % 128 == 0

    float* myrow = &buf[tid * ROWS];
    const float4* Er = (const float4*)(E + e * DIM);
#pragma unroll
    for (int i = 0; i < 16; ++i) {
        float4 v = Er[i];
        myrow[4*i+0] = v.x; myrow[4*i+1] = v.y;
        myrow[4*i+2] = v.z; myrow[4*i+3] = v.w;
    }

    float x[DIM];

    // layer 1
#pragma unroll
    for (int j = 0; j < DIM; ++j) x[j] = b1[j];
    for (int k = 0; k < DIM; ++k) {
        const float a = myrow[k];
        const float* w = &w1[k * DIM];
#pragma unroll
        for (int j = 0; j < DIM; ++j) x[j] = fmaf(a, w[j], x[j]);
    }
#pragma unroll
    for (int j = 0; j < DIM; ++j) myrow[j] = fmaxf(x[j], 0.f);

    // layer 2
#pragma unroll
    for (int j = 0; j < DIM; ++j) x[j] = b2[j];
    for (int k = 0; k < DIM; ++k) {
        const float a = myrow[k];
        const float* w = &w2[k * DIM];
#pragma unroll
        for (int j = 0; j < DIM; ++j) x[j] = fmaf(a, w[j], x[j]);
    }
#pragma unroll
    for (int j = 0; j < DIM; ++j) myrow[j] = fmaxf(x[j], 0.f);

    // gate
#pragma unroll
    for (int j = 0; j < DIM; ++j) x[j] = Bb[j];
    for (int k = 0; k < DIM; ++k) {
        const float a = myrow[k];
        const float* w = &Bw[k * DIM];
#pragma unroll
        for (int j = 0; j < DIM; ++j) x[j] = fmaf(a, w[j], x[j]);
    }
    float scale[DIM];
#pragma unroll
    for (int j = 0; j < DIM; ++j) scale[j] = 1.f / (1.f + __expf(-x[j]));

    // shift
#pragma unroll
    for (int j = 0; j < DIM; ++j) x[j] = Cb[j];
    for (int k = 0; k < DIM; ++k) {
        const float a = myrow[k];
        const float* w = &Cw[k * DIM];
#pragma unroll
        for (int j = 0; j < DIM; ++j) x[j] = fmaf(a, w[j], x[j]);
    }

    // gather + message + packed bf16 store
    const int s = src[e];
    const float4* Vr = (const float4*)(Vp + (size_t)s * DIM);
    uint2* orow = (uint2*)(msg + e * DIM);
#pragma unroll
    for (int i = 0; i < 16; ++i) {
        float4 v = Vr[i];
        float m0 = fmaf(scale[4*i+0], v.x, x[4*i+0]); m0 = fmaxf(m0, EPS); m0 *= m0;
        float m1 = fmaf(scale[4*i+1], v.y, x[4*i+1]); m1 = fmaxf(m1, EPS); m1 *= m1;
        float m2 = fmaf(scale[4*i+2], v.z, x[4*i+2]); m2 = fmaxf(m2, EPS); m2 *= m2;
        float m3 = fmaf(scale[4*i+3], v.w, x[4*i+3]); m3 = fmaxf(m3, EPS); m3 *= m3;
        uint2 p;
        p.x = pack2bf(m0, m1);
        p.y = pack2bf(m2, m3);
        orow[i] = p;
    }
}

// ---------------------------------------------------------------------------
// Aggregate: one wave per node, lane = dim. sum msg over edge list, sqrt(mean)
// ---------------------------------------------------------------------------
__global__ __launch_bounds__(256) void aggregate_kernel(
    const __hip_bfloat16* __restrict__ msg, const int* __restrict__ eidx,
    const int* __restrict__ offs, const int* __restrict__ cnt,
    float* __restrict__ out)
{
    const int n = (blockIdx.x * 256 + threadIdx.x) >> 6;   // global wave id
    const int lane = threadIdx.x & 63;
    if (n >= N_NODES) return;
    const int start = offs[n];
    const int deg = cnt[n];
    float acc = 0.f;
    int i = 0;
    for (; i + 1 < deg; i += 2) {
        const int e0 = eidx[start + i];
        const int e1 = eidx[start + i + 1];
        const float a = __bfloat162float(msg[(size_t)e0 * DIM + lane]);
        const float b = __bfloat162float(msg[(size_t)e1 * DIM + lane]);
        acc += a + b;
    }
    if (i < deg) {
        const int e0 = eidx[start + i];
        acc += __bfloat162float(msg[(size_t)e0 * DIM + lane]);
    }
    const float dinv = (deg > 0) ? 1.0f / (float)deg : 0.0f;
    out[(size_t)n * DIM + lane] = sqrtf(acc * dinv);
}

// ---------------------------------------------------------------------------
// Fallback path (round-1 style) if ws_size is too small for the CSR buffers
// ---------------------------------------------------------------------------
__global__ __launch_bounds__(128) void edge_atomic_kernel(
    const float* __restrict__ E,
    const int* __restrict__ src, const int* __restrict__ dst,
    const float* __restrict__ w1, const float* __restrict__ b1,
    const float* __restrict__ w2, const float* __restrict__ b2,
    const float* __restrict__ Bw, const float* __restrict__ Bb,
    const float* __restrict__ Cw, const float* __restrict__ Cb,
    const float* __restrict__ Vp,
    float* __restrict__ ssum, float* __restrict__ cntf)
{
    __shared__ float buf[128 * ROWS];
    const int tid = threadIdx.x;
    const size_t e = (size_t)blockIdx.x * 128 + tid;

    float* myrow = &buf[tid * ROWS];
    const float4* Er = (const float4*)(E + e * DIM);
#pragma unroll
    for (int i = 0; i < 16; ++i) {
        float4 v = Er[i];
        myrow[4*i+0] = v.x; myrow[4*i+1] = v.y;
        myrow[4*i+2] = v.z; myrow[4*i+3] = v.w;
    }
    float x[DIM];
#pragma unroll
    for (int j = 0; j < DIM; ++j) x[j] = b1[j];
    for (int k = 0; k < DIM; ++k) {
        const float a = myrow[k]; const float* w = &w1[k * DIM];
#pragma unroll
        for (int j = 0; j < DIM; ++j) x[j] = fmaf(a, w[j], x[j]);
    }
#pragma unroll
    for (int j = 0; j < DIM; ++j) myrow[j] = fmaxf(x[j], 0.f);
#pragma unroll
    for (int j = 0; j < DIM; ++j) x[j] = b2[j];
    for (int k = 0; k < DIM; ++k) {
        const float a = myrow[k]; const float* w = &w2[k * DIM];
#pragma unroll
        for (int j = 0; j < DIM; ++j) x[j] = fmaf(a, w[j], x[j]);
    }
#pragma unroll
    for (int j = 0; j < DIM; ++j) myrow[j] = fmaxf(x[j], 0.f);
#pragma unroll
    for (int j = 0; j < DIM; ++j) x[j] = Bb[j];
    for (int k = 0; k < DIM; ++k) {
        const float a = myrow[k]; const float* w = &Bw[k * DIM];
#pragma unroll
        for (int j = 0; j < DIM; ++j) x[j] = fmaf(a, w[j], x[j]);
    }
    float scale[DIM];
#pragma unroll
    for (int j = 0; j < DIM; ++j) scale[j] = 1.f / (1.f + __expf(-x[j]));
#pragma unroll
    for (int j = 0; j < DIM; ++j) x[j] = Cb[j];
    for (int k = 0; k < DIM; ++k) {
        const float a = myrow[k]; const float* w = &Cw[k * DIM];
#pragma unroll
        for (int j = 0; j < DIM; ++j) x[j] = fmaf(a, w[j], x[j]);
    }
    const int s = src[e];
    const int d = dst[e];
    const float4* Vr = (const float4*)(Vp + (size_t)s * DIM);
    float* srow = ssum + (size_t)d * DIM;
#pragma unroll
    for (int i = 0; i < 16; ++i) {
        float4 v = Vr[i];
        float m;
        m = fmaf(scale[4*i+0], v.x, x[4*i+0]); m = fmaxf(m, EPS); atomicAdd(&srow[4*i+0], m*m);
        m = fmaf(scale[4*i+1], v.y, x[4*i+1]); m = fmaxf(m, EPS); atomicAdd(&srow[4*i+1], m*m);
        m = fmaf(scale[4*i+2], v.z, x[4*i+2]); m = fmaxf(m, EPS); atomicAdd(&srow[4*i+2], m*m);
        m = fmaf(scale[4*i+3], v.w, x[4*i+3]); m = fmaxf(m, EPS); atomicAdd(&srow[4*i+3], m*m);
    }
    atomicAdd(&cntf[d], 1.0f);
}

__global__ __launch_bounds__(256) void finalize_kernel(
    float* __restrict__ out, const float* __restrict__ cntf)
{
    const size_t i = (size_t)blockIdx.x * 256 + threadIdx.x;
    if (i >= (size_t)N_NODES * DIM / 4) return;
    const float c = fmaxf(cntf[i >> 4], 1.0f);
    const float rc = 1.0f / c;
    float4* p = ((float4*)out) + i;
    float4 v = *p;
    v.x = sqrtf(v.x * rc); v.y = sqrtf(v.y * rc);
    v.z = sqrtf(v.z * rc); v.w = sqrtf(v.w * rc);
    *p = v;
}

extern "C" void kernel_launch(void* const* d_in, const int* in_sizes, int n_in,
                              void* d_out, int out_size, void* d_ws, size_t ws_size,
                              hipStream_t stream) {
    const float* V   = (const float*)d_in[0];
    const float* E   = (const float*)d_in[1];
    const int*   src = (const int*)d_in[2];
    const int*   dst = (const int*)d_in[3];
    const float* w1  = (const float*)d_in[4];
    const float* b1  = (const float*)d_in[5];
    const float* w2  = (const float*)d_in[6];
    const float* b2  = (const float*)d_in[7];
    const float* Bw  = (const float*)d_in[8];
    const float* Bb  = (const float*)d_in[9];
    const float* Cw  = (const float*)d_in[10];
    const float* Cb  = (const float*)d_in[11];
    const float* pAw = (const float*)d_in[12];
    const float* pAb = (const float*)d_in[13];
    const float* pBw = (const float*)d_in[14];
    const float* pBb = (const float*)d_in[15];

    float* out = (float*)d_out;

    // workspace layout
    char* p = (char*)d_ws;
    float* Vp = (float*)p;                 p += (size_t)N_NODES * DIM * sizeof(float);   // 12.8 MB
    const size_t need_csr =
        (size_t)N_NODES * DIM * 4 +            // Vp
        (size_t)N_EDGES * DIM * 2 +            // msg bf16
        (size_t)N_NODES * 4 * 3 +              // cnt, offs, cursor
        (size_t)N_EDGES * 4;                   // eidx

    if (ws_size >= need_csr) {
        __hip_bfloat16* msg = (__hip_bfloat16*)p; p += (size_t)N_EDGES * DIM * 2;  // 102.4 MB
        int* cnt    = (int*)p; p += (size_t)N_NODES * 4;
        int* offs   = (int*)p; p += (size_t)N_NODES * 4;
        int* cursor = (int*)p; p += (size_t)N_NODES * 4;
        int* eidx   = (int*)p; p += (size_t)N_EDGES * 4;

        hipMemsetAsync(cnt, 0, (size_t)N_NODES * sizeof(int), stream);

        node_kernel<<<(N_NODES + 127) / 128, 128, 0, stream>>>(V, pAw, pAb, pBw, pBb, Vp);
        hist_kernel<<<N_EDGES / 256, 256, 0, stream>>>(dst, cnt);
        scan_kernel<<<1, SCAN_T, 0, stream>>>(cnt, offs, cursor);
        scatter_kernel<<<N_EDGES / 256, 256, 0, stream>>>(dst, cursor, eidx);
        edge_kernel<<<N_EDGES / 128, 128, 0, stream>>>(E, src, w1, b1, w2, b2,
                                                       Bw, Bb, Cw, Cb, Vp, msg);
        aggregate_kernel<<<(N_NODES * 64 + 255) / 256, 256, 0, stream>>>(msg, eidx, offs, cnt, out);
    } else {
        // fallback: atomic path
        float* cntf = (float*)p;
        hipMemsetAsync(d_out, 0, (size_t)N_NODES * DIM * sizeof(float), stream);
        hipMemsetAsync(cntf, 0, (size_t)N_NODES * sizeof(float), stream);
        node_kernel<<<(N_NODES + 127) / 128, 128, 0, stream>>>(V, pAw, pAb, pBw, pBb, Vp);
        edge_atomic_kernel<<<N_EDGES / 128, 128, 0, stream>>>(E, src, dst, w1, b1, w2, b2,
                                                              Bw, Bb, Cw, Cb, Vp, out, cntf);
        finalize_kernel<<<(N_NODES * DIM / 4 + 255) / 256, 256, 0, stream>>>(out, cntf);
    }
}

// Round 3
// 418.969 us; speedup vs baseline: 6.7170x; 2.1212x over previous
//
#include <hip/hip_runtime.h>
#include <hip/hip_bf16.h>
#include <math.h>

// Problem constants (match reference)
#define N_NODES 50000
#define N_EDGES 800000
#define DIM 64
#define NEG_SLOPE 0.2f
#define EPS 1e-5f

typedef __attribute__((ext_vector_type(8))) short short8v;  // 8 bf16 (4 VGPRs)
typedef __attribute__((ext_vector_type(4))) float f32x4;    // MFMA accumulator

__device__ __forceinline__ float lrelu(float v) { return fmaxf(v, NEG_SLOPE * v); }

__device__ __forceinline__ unsigned short bfbits(float v) {
    return __bfloat16_as_ushort(__float2bfloat16(v));
}
__device__ __forceinline__ unsigned pack2bf(float a, float b) {
    return (unsigned)bfbits(a) | ((unsigned)bfbits(b) << 16);
}

// Swizzled byte offset into a 128-byte-stride LDS tile (T2: byte ^= (row&7)<<4).
// Bijective within each row; keeps 16B alignment for b128 ops.
__device__ __forceinline__ unsigned swz(unsigned row, unsigned byteInRow) {
    return row * 128u + (byteInRow ^ ((row & 7u) << 4));
}

// ---------------------------------------------------------------------------
// Node pooling (unchanged, fp32 VALU): Vp = lrelu(lrelu(V)@pAw+pAb)@pBw+pBb
// ---------------------------------------------------------------------------
#define ROWS 65
__global__ __launch_bounds__(128) void node_kernel(
    const float* __restrict__ V,
    const float* __restrict__ pAw, const float* __restrict__ pAb,
    const float* __restrict__ pBw, const float* __restrict__ pBb,
    float* __restrict__ Vp)
{
    __shared__ float buf[128 * ROWS];
    const int tid = threadIdx.x;
    const size_t n = (size_t)blockIdx.x * 128 + tid;
    if (n >= N_NODES) return;

    float* myrow = &buf[tid * ROWS];
    const float4* Vr = (const float4*)(V + n * DIM);
#pragma unroll
    for (int i = 0; i < 16; ++i) {
        float4 v = Vr[i];
        myrow[4*i+0] = lrelu(v.x); myrow[4*i+1] = lrelu(v.y);
        myrow[4*i+2] = lrelu(v.z); myrow[4*i+3] = lrelu(v.w);
    }
    float x[DIM];
#pragma unroll
    for (int j = 0; j < DIM; ++j) x[j] = pAb[j];
    for (int k = 0; k < DIM; ++k) {
        const float a = myrow[k]; const float* w = &pAw[k * DIM];
#pragma unroll
        for (int j = 0; j < DIM; ++j) x[j] = fmaf(a, w[j], x[j]);
    }
#pragma unroll
    for (int j = 0; j < DIM; ++j) myrow[j] = lrelu(x[j]);
#pragma unroll
    for (int j = 0; j < DIM; ++j) x[j] = pBb[j];
    for (int k = 0; k < DIM; ++k) {
        const float a = myrow[k]; const float* w = &pBw[k * DIM];
#pragma unroll
        for (int j = 0; j < DIM; ++j) x[j] = fmaf(a, w[j], x[j]);
    }
    float4* Od = (float4*)(Vp + n * DIM);
#pragma unroll
    for (int i = 0; i < 16; ++i) {
        float4 v; v.x = x[4*i+0]; v.y = x[4*i+1]; v.z = x[4*i+2]; v.w = x[4*i+3];
        Od[i] = v;
    }
}

// ---------------------------------------------------------------------------
// CSR build: histogram -> single-block scan -> per-edge slot (epos)
// ---------------------------------------------------------------------------
__global__ __launch_bounds__(256) void hist_kernel(
    const int* __restrict__ dst, int* __restrict__ cnt)
{
    const int e = blockIdx.x * 256 + threadIdx.x;   // 800000 % 256 == 0
    atomicAdd(&cnt[dst[e]], 1);
}

#define SCAN_T 1024
#define SCAN_C 49   // 1024*49 = 50176 >= 50000
__global__ __launch_bounds__(SCAN_T) void scan_kernel(
    const int* __restrict__ cnt, int* __restrict__ offs, int* __restrict__ cursor)
{
    __shared__ int ts[SCAN_T];
    const int t = threadIdx.x;
    const int base = t * SCAN_C;
    int s = 0;
    for (int i = 0; i < SCAN_C; ++i) {
        const int idx = base + i;
        s += (idx < N_NODES) ? cnt[idx] : 0;
    }
    ts[t] = s;
    __syncthreads();
    for (int off = 1; off < SCAN_T; off <<= 1) {
        const int add = (t >= off) ? ts[t - off] : 0;
        __syncthreads();
        ts[t] += add;
        __syncthreads();
    }
    int run = (t == 0) ? 0 : ts[t - 1];
    for (int i = 0; i < SCAN_C; ++i) {
        const int idx = base + i;
        if (idx < N_NODES) { offs[idx] = run; cursor[idx] = run; run += cnt[idx]; }
    }
}

__global__ __launch_bounds__(256) void scatter_kernel(
    const int* __restrict__ dst, int* __restrict__ cursor, int* __restrict__ epos)
{
    const int e = blockIdx.x * 256 + threadIdx.x;
    epos[e] = atomicAdd(&cursor[dst[e]], 1);
}

// ---------------------------------------------------------------------------
// MFMA edge pipeline. Block = 128 edges, 256 threads = 4 waves.
// Wave w computes out-dims [16w,16w+16) for all 128 edges of the tile.
// LDS tiles (bf16, swizzled): bufA/bufB ping-pong E -> x1 -> x2 -> msg.
// Writes msg row to its CSR slot (epos) so aggregation reads contiguously.
// ---------------------------------------------------------------------------
#define LDS_BUF 16384  // 128 rows x 128 bytes
__global__ __launch_bounds__(256) void edge_kernel(
    const float* __restrict__ E,
    const int* __restrict__ src, const int* __restrict__ epos,
    const float* __restrict__ w1, const float* __restrict__ b1,
    const float* __restrict__ w2, const float* __restrict__ b2,
    const float* __restrict__ Bw, const float* __restrict__ Bb,
    const float* __restrict__ Cw, const float* __restrict__ Cb,
    const float* __restrict__ Vp,
    __hip_bfloat16* __restrict__ msg)
{
    __shared__ __align__(16) unsigned char sm[2 * LDS_BUF + 128 * 4 * 2];
    unsigned char* bufA = sm;
    unsigned char* bufB = sm + LDS_BUF;
    int* srcv  = (int*)(sm + 2 * LDS_BUF);
    int* eposv = (int*)(sm + 2 * LDS_BUF + 128 * 4);

    const int t    = threadIdx.x;
    const int w    = t >> 6;        // wave id 0..3
    const int lane = t & 63;
    const int g    = lane >> 4;     // k-chunk group
    const int c    = lane & 15;     // row (A) / col (B,C) index
    const int col  = 16 * w + c;    // this lane's output dim
    const unsigned colbyte = (unsigned)col * 2;
    const int base = blockIdx.x * 128;

    // ---- stage: src/epos + E tile (fp32 -> bf16, swizzled) ----
    if (t < 128) { srcv[t] = src[base + t]; eposv[t] = epos[base + t]; }
    {
        const int row = t >> 1;
        const float4* Ep = (const float4*)(E + (size_t)(base + row) * DIM + (t & 1) * 32);
#pragma unroll
        for (int ci = 0; ci < 4; ++ci) {
            float4 qa = Ep[2 * ci];
            float4 qb = Ep[2 * ci + 1];
            uint4 u;
            u.x = pack2bf(qa.x, qa.y); u.y = pack2bf(qa.z, qa.w);
            u.z = pack2bf(qb.x, qb.y); u.w = pack2bf(qb.z, qb.w);
            *(uint4*)(bufA + swz(row, (t & 1) * 64 + 16 * ci)) = u;
        }
    }

    // ---- weight B-fragments (bf16, registers, reused for all M-tiles) ----
    // B[k][n] row-major; lane holds col=c(+16w), k = 32*kstep + 8*g + j.
#define LOAD_WF(W, ks, frag)                                                  \
    {                                                                         \
        _Pragma("unroll")                                                     \
        for (int j = 0; j < 8; ++j)                                           \
            frag[j] = (short)bfbits(W[(32 * (ks) + 8 * g + j) * DIM + col]);  \
    }
    short8v w1f0, w1f1, w2f0, w2f1, bwf0, bwf1, cwf0, cwf1;
    LOAD_WF(w1, 0, w1f0); LOAD_WF(w1, 1, w1f1);
    LOAD_WF(w2, 0, w2f0); LOAD_WF(w2, 1, w2f1);
    LOAD_WF(Bw, 0, bwf0); LOAD_WF(Bw, 1, bwf1);
    LOAD_WF(Cw, 0, cwf0); LOAD_WF(Cw, 1, cwf1);
    const float bb1 = b1[col], bb2 = b2[col], bbB = Bb[col], bbC = Cb[col];

    __syncthreads();

    // ---- layer 1: x1 = relu(E @ w1 + b1) : bufA -> bufB ----
#pragma unroll
    for (int mt = 0; mt < 8; ++mt) {
        const int arow = mt * 16 + c;
        short8v a0 = *(const short8v*)(bufA + swz(arow, 16 * g));
        short8v a1 = *(const short8v*)(bufA + swz(arow, 64 + 16 * g));
        f32x4 acc = {0.f, 0.f, 0.f, 0.f};
        acc = __builtin_amdgcn_mfma_f32_16x16x32_bf16(a0, w1f0, acc, 0, 0, 0);
        acc = __builtin_amdgcn_mfma_f32_16x16x32_bf16(a1, w1f1, acc, 0, 0, 0);
#pragma unroll
        for (int r = 0; r < 4; ++r) {
            const float v = fmaxf(acc[r] + bb1, 0.f);
            *(unsigned short*)(bufB + swz(mt * 16 + 4 * g + r, colbyte)) = bfbits(v);
        }
    }
    __syncthreads();

    // ---- layer 2: x2 = relu(x1 @ w2 + b2) : bufB -> bufA ----
#pragma unroll
    for (int mt = 0; mt < 8; ++mt) {
        const int arow = mt * 16 + c;
        short8v a0 = *(const short8v*)(bufB + swz(arow, 16 * g));
        short8v a1 = *(const short8v*)(bufB + swz(arow, 64 + 16 * g));
        f32x4 acc = {0.f, 0.f, 0.f, 0.f};
        acc = __builtin_amdgcn_mfma_f32_16x16x32_bf16(a0, w2f0, acc, 0, 0, 0);
        acc = __builtin_amdgcn_mfma_f32_16x16x32_bf16(a1, w2f1, acc, 0, 0, 0);
#pragma unroll
        for (int r = 0; r < 4; ++r) {
            const float v = fmaxf(acc[r] + bb2, 0.f);
            *(unsigned short*)(bufA + swz(mt * 16 + 4 * g + r, colbyte)) = bfbits(v);
        }
    }
    __syncthreads();

    // ---- gate + shift GEMMs from x2 (bufA), concurrent accumulators ----
    f32x4 ag[8], as_[8];
#pragma unroll
    for (int mt = 0; mt < 8; ++mt) {
        const int arow = mt * 16 + c;
        short8v a0 = *(const short8v*)(bufA + swz(arow, 16 * g));
        short8v a1 = *(const short8v*)(bufA + swz(arow, 64 + 16 * g));
        f32x4 t0 = {0.f, 0.f, 0.f, 0.f};
        t0 = __builtin_amdgcn_mfma_f32_16x16x32_bf16(a0, bwf0, t0, 0, 0, 0);
        t0 = __builtin_amdgcn_mfma_f32_16x16x32_bf16(a1, bwf1, t0, 0, 0, 0);
        ag[mt] = t0;
        f32x4 t1 = {0.f, 0.f, 0.f, 0.f};
        t1 = __builtin_amdgcn_mfma_f32_16x16x32_bf16(a0, cwf0, t1, 0, 0, 0);
        t1 = __builtin_amdgcn_mfma_f32_16x16x32_bf16(a1, cwf1, t1, 0, 0, 0);
        as_[mt] = t1;
    }

    // ---- gather Vp[src], msg = (sigmoid(gate)*vp + shift), M = max(msg,EPS)^2
    // C layout: col = lane&15(+16w), edge-row = mt*16 + 4*g + r.
    // msg tile -> bufB (x1 dead; all waves past layer-2 barrier).
#pragma unroll
    for (int mt = 0; mt < 8; ++mt) {
#pragma unroll
        for (int r = 0; r < 4; ++r) {
            const int eloc = mt * 16 + 4 * g + r;
            const int sv = srcv[eloc];
            const float vp = Vp[(size_t)sv * DIM + col];
            const float gate = 1.f / (1.f + __expf(-(ag[mt][r] + bbB)));
            const float sh = as_[mt][r] + bbC;
            float m = fmaf(gate, vp, sh);
            m = fmaxf(m, EPS);
            m = m * m;
            *(unsigned short*)(bufB + swz(eloc, colbyte)) = bfbits(m);
        }
    }
    __syncthreads();

    // ---- copy-out to CSR slot: 2 threads per edge row, 64B each ----
    {
        const int row = t >> 1;
        const int pos = eposv[row];
        uint4 v[4];
#pragma unroll
        for (int ci = 0; ci < 4; ++ci)
            v[ci] = *(const uint4*)(bufB + swz(row, (t & 1) * 64 + 16 * ci));
        uint4* dp = (uint4*)((unsigned short*)msg + (size_t)pos * DIM + (t & 1) * 32);
#pragma unroll
        for (int ci = 0; ci < 4; ++ci) dp[ci] = v[ci];
    }
}

// ---------------------------------------------------------------------------
// Aggregate: one wave per node, lane = dim. msg rows are CSR-contiguous.
// ---------------------------------------------------------------------------
__global__ __launch_bounds__(256) void aggregate_kernel(
    const __hip_bfloat16* __restrict__ msg,
    const int* __restrict__ offs, const int* __restrict__ cnt,
    float* __restrict__ out)
{
    const int n = (blockIdx.x * 256 + threadIdx.x) >> 6;
    const int lane = threadIdx.x & 63;
    if (n >= N_NODES) return;
    const int start = offs[n];
    const int deg = cnt[n];
    const __hip_bfloat16* p = msg + (size_t)start * DIM + lane;
    float acc = 0.f;
    int i = 0;
    for (; i + 4 <= deg; i += 4) {
        const float a0 = __bfloat162float(p[(size_t)(i + 0) * DIM]);
        const float a1 = __bfloat162float(p[(size_t)(i + 1) * DIM]);
        const float a2 = __bfloat162float(p[(size_t)(i + 2) * DIM]);
        const float a3 = __bfloat162float(p[(size_t)(i + 3) * DIM]);
        acc += (a0 + a1) + (a2 + a3);
    }
    for (; i < deg; ++i) acc += __bfloat162float(p[(size_t)i * DIM]);
    const float dinv = (deg > 0) ? 1.0f / (float)deg : 0.0f;
    out[(size_t)n * DIM + lane] = sqrtf(acc * dinv);
}

extern "C" void kernel_launch(void* const* d_in, const int* in_sizes, int n_in,
                              void* d_out, int out_size, void* d_ws, size_t ws_size,
                              hipStream_t stream) {
    const float* V   = (const float*)d_in[0];
    const float* E   = (const float*)d_in[1];
    const int*   src = (const int*)d_in[2];
    const int*   dst = (const int*)d_in[3];
    const float* w1  = (const float*)d_in[4];
    const float* b1  = (const float*)d_in[5];
    const float* w2  = (const float*)d_in[6];
    const float* b2  = (const float*)d_in[7];
    const float* Bw  = (const float*)d_in[8];
    const float* Bb  = (const float*)d_in[9];
    const float* Cw  = (const float*)d_in[10];
    const float* Cb  = (const float*)d_in[11];
    const float* pAw = (const float*)d_in[12];
    const float* pAb = (const float*)d_in[13];
    const float* pBw = (const float*)d_in[14];
    const float* pBb = (const float*)d_in[15];

    float* out = (float*)d_out;

    // workspace layout
    char* p = (char*)d_ws;
    float* Vp = (float*)p;                    p += (size_t)N_NODES * DIM * sizeof(float);
    __hip_bfloat16* msg = (__hip_bfloat16*)p; p += (size_t)N_EDGES * DIM * 2;
    int* cnt    = (int*)p; p += (size_t)N_NODES * 4;
    int* offs   = (int*)p; p += (size_t)N_NODES * 4;
    int* cursor = (int*)p; p += (size_t)N_NODES * 4;
    int* epos   = (int*)p; p += (size_t)N_EDGES * 4;

    hipMemsetAsync(cnt, 0, (size_t)N_NODES * sizeof(int), stream);

    node_kernel<<<(N_NODES + 127) / 128, 128, 0, stream>>>(V, pAw, pAb, pBw, pBb, Vp);
    hist_kernel<<<N_EDGES / 256, 256, 0, stream>>>(dst, cnt);
    scan_kernel<<<1, SCAN_T, 0, stream>>>(cnt, offs, cursor);
    scatter_kernel<<<N_EDGES / 256, 256, 0, stream>>>(dst, cursor, epos);
    edge_kernel<<<N_EDGES / 128, 256, 0, stream>>>(E, src, epos, w1, b1, w2, b2,
                                                   Bw, Bb, Cw, Cb, Vp, msg);
    aggregate_kernel<<<(N_NODES * 64 + 255) / 256, 256, 0, stream>>>(msg, offs, cnt, out);
}

// Round 5
// 311.055 us; speedup vs baseline: 9.0473x; 1.3469x over previous
//
#include <hip/hip_runtime.h>
#include <hip/hip_bf16.h>
#include <math.h>

// Problem constants (match reference)
#define N_NODES 50000
#define N_EDGES 800000
#define DIM 64
#define NEG_SLOPE 0.2f
#define EPS 1e-5f

typedef __attribute__((ext_vector_type(8))) short short8v;  // 8 bf16 (4 VGPRs)
typedef __attribute__((ext_vector_type(4))) float f32x4;    // MFMA accumulator

__device__ __forceinline__ float lrelu(float v) { return fmaxf(v, NEG_SLOPE * v); }

__device__ __forceinline__ unsigned short bfbits(float v) {
    return __bfloat16_as_ushort(__float2bfloat16(v));
}
// packed pair f32->bf16 (compiler lowers to v_cvt_pk_bf16_f32)
__device__ __forceinline__ unsigned pack2bf(float a, float b) {
    union { __hip_bfloat162 h; unsigned u; } cvt;
    cvt.h = __float22bfloat162_rn(make_float2(a, b));
    return cvt.u;
}

// Swizzled byte offset into a 128-byte-stride LDS tile (T2: byte ^= (row&7)<<4).
__device__ __forceinline__ unsigned swz(unsigned row, unsigned byteInRow) {
    return row * 128u + (byteInRow ^ ((row & 7u) << 4));
}

// weight B-fragment loader: W row-major [64][64]; lane holds col, k = 32*ks+8*g+j
#define LOAD_WF(W, ks, frag)                                                  \
    {                                                                         \
        _Pragma("unroll")                                                     \
        for (int j = 0; j < 8; ++j)                                           \
            frag[j] = (short)bfbits(W[(32 * (ks) + 8 * g + j) * DIM + col]);  \
    }

#define LDS_BUF 16384  // 128 rows x 128 bytes

// ---------------------------------------------------------------------------
// Node pooling via MFMA: Vp = lrelu(lrelu(V)@pAw+pAb)@pBw+pBb
// Block = 128 nodes, 256 threads = 4 waves; wave w owns out-dims [16w,16w+16).
// ---------------------------------------------------------------------------
__global__ __launch_bounds__(256) void node_kernel(
    const float* __restrict__ V,
    const float* __restrict__ pAw, const float* __restrict__ pAb,
    const float* __restrict__ pBw, const float* __restrict__ pBb,
    float* __restrict__ Vp)
{
    __shared__ __align__(16) unsigned char sm[2 * LDS_BUF];
    unsigned char* bufA = sm;
    unsigned char* bufB = sm + LDS_BUF;

    const int t    = threadIdx.x;
    const int w    = t >> 6;
    const int lane = t & 63;
    const int g    = lane >> 4;
    const int c    = lane & 15;
    const int col  = 16 * w + c;
    const unsigned colbyte = (unsigned)col * 2;
    const int base = blockIdx.x * 128;

    // stage lrelu(V) rows -> bufA (bf16, swizzled); zero-fill past N_NODES
    {
        const int row = t >> 1;
        const int n = base + row;
        if (n < N_NODES) {
            const float4* Vr = (const float4*)(V + (size_t)n * DIM + (t & 1) * 32);
#pragma unroll
            for (int ci = 0; ci < 4; ++ci) {
                float4 qa = Vr[2 * ci];
                float4 qb = Vr[2 * ci + 1];
                uint4 u;
                u.x = pack2bf(lrelu(qa.x), lrelu(qa.y));
                u.y = pack2bf(lrelu(qa.z), lrelu(qa.w));
                u.z = pack2bf(lrelu(qb.x), lrelu(qb.y));
                u.w = pack2bf(lrelu(qb.z), lrelu(qb.w));
                *(uint4*)(bufA + swz(row, (t & 1) * 64 + 16 * ci)) = u;
            }
        } else {
            uint4 z = {0u, 0u, 0u, 0u};
#pragma unroll
            for (int ci = 0; ci < 4; ++ci)
                *(uint4*)(bufA + swz(row, (t & 1) * 64 + 16 * ci)) = z;
        }
    }

    short8v af0, af1, bf0, bf1;
    LOAD_WF(pAw, 0, af0); LOAD_WF(pAw, 1, af1);
    LOAD_WF(pBw, 0, bf0); LOAD_WF(pBw, 1, bf1);
    const float bbA = pAb[col], bbB = pBb[col];

    __syncthreads();

    // layer A: lrelu(x @ pAw + pAb) : bufA -> bufB
#pragma unroll
    for (int mt = 0; mt < 8; ++mt) {
        const int arow = mt * 16 + c;
        short8v a0 = *(const short8v*)(bufA + swz(arow, 16 * g));
        short8v a1 = *(const short8v*)(bufA + swz(arow, 64 + 16 * g));
        f32x4 acc = {0.f, 0.f, 0.f, 0.f};
        acc = __builtin_amdgcn_mfma_f32_16x16x32_bf16(a0, af0, acc, 0, 0, 0);
        acc = __builtin_amdgcn_mfma_f32_16x16x32_bf16(a1, af1, acc, 0, 0, 0);
#pragma unroll
        for (int r = 0; r < 4; ++r) {
            const float v = lrelu(acc[r] + bbA);
            *(unsigned short*)(bufB + swz(mt * 16 + 4 * g + r, colbyte)) = bfbits(v);
        }
    }
    __syncthreads();

    // layer B: x @ pBw + pBb : bufB -> global Vp (fp32)
#pragma unroll
    for (int mt = 0; mt < 8; ++mt) {
        const int arow = mt * 16 + c;
        short8v a0 = *(const short8v*)(bufB + swz(arow, 16 * g));
        short8v a1 = *(const short8v*)(bufB + swz(arow, 64 + 16 * g));
        f32x4 acc = {0.f, 0.f, 0.f, 0.f};
        acc = __builtin_amdgcn_mfma_f32_16x16x32_bf16(a0, bf0, acc, 0, 0, 0);
        acc = __builtin_amdgcn_mfma_f32_16x16x32_bf16(a1, bf1, acc, 0, 0, 0);
#pragma unroll
        for (int r = 0; r < 4; ++r) {
            const int n = base + mt * 16 + 4 * g + r;
            if (n < N_NODES) Vp[(size_t)n * DIM + col] = acc[r] + bbB;
        }
    }
}

// ---------------------------------------------------------------------------
// hist: per-dst count AND per-edge rank (slot within its node)
// ---------------------------------------------------------------------------
__global__ __launch_bounds__(256) void hist_kernel(
    const int* __restrict__ dst, int* __restrict__ cnt, int* __restrict__ rank)
{
    const int e = blockIdx.x * 256 + threadIdx.x;   // 800000 % 256 == 0
    rank[e] = atomicAdd(&cnt[dst[e]], 1);
}

#define SCAN_T 1024
#define SCAN_C 49   // 1024*49 = 50176 >= 50000
__global__ __launch_bounds__(SCAN_T) void scan_kernel(
    const int* __restrict__ cnt, int* __restrict__ offs)
{
    __shared__ int ts[SCAN_T];
    const int t = threadIdx.x;
    const int base = t * SCAN_C;
    int s = 0;
    for (int i = 0; i < SCAN_C; ++i) {
        const int idx = base + i;
        s += (idx < N_NODES) ? cnt[idx] : 0;
    }
    ts[t] = s;
    __syncthreads();
    for (int off = 1; off < SCAN_T; off <<= 1) {
        const int add = (t >= off) ? ts[t - off] : 0;
        __syncthreads();
        ts[t] += add;
        __syncthreads();
    }
    int run = (t == 0) ? 0 : ts[t - 1];
    for (int i = 0; i < SCAN_C; ++i) {
        const int idx = base + i;
        if (idx < N_NODES) { offs[idx] = run; run += cnt[idx]; }
    }
}

// ---------------------------------------------------------------------------
// MFMA edge pipeline. Block = 128 edges, 256 threads = 4 waves.
// Writes msg row to CSR slot offs[dst]+rank so aggregation reads contiguously.
// ---------------------------------------------------------------------------
__global__ __launch_bounds__(256) void edge_kernel(
    const float* __restrict__ E,
    const int* __restrict__ src, const int* __restrict__ dst,
    const int* __restrict__ rank, const int* __restrict__ offs,
    const float* __restrict__ w1, const float* __restrict__ b1,
    const float* __restrict__ w2, const float* __restrict__ b2,
    const float* __restrict__ Bw, const float* __restrict__ Bb,
    const float* __restrict__ Cw, const float* __restrict__ Cb,
    const float* __restrict__ Vp,
    __hip_bfloat16* __restrict__ msg)
{
    __shared__ __align__(16) unsigned char sm[2 * LDS_BUF + 128 * 4 * 2];
    unsigned char* bufA = sm;
    unsigned char* bufB = sm + LDS_BUF;
    int* srcv  = (int*)(sm + 2 * LDS_BUF);
    int* eposv = (int*)(sm + 2 * LDS_BUF + 128 * 4);

    const int t    = threadIdx.x;
    const int w    = t >> 6;
    const int lane = t & 63;
    const int g    = lane >> 4;
    const int c    = lane & 15;
    const int col  = 16 * w + c;
    const unsigned colbyte = (unsigned)col * 2;
    const int base = blockIdx.x * 128;

    // ---- stage: src + CSR slot + E tile (fp32 -> bf16, swizzled) ----
    if (t < 128) {
        srcv[t] = src[base + t];
        eposv[t] = offs[dst[base + t]] + rank[base + t];
    }
    {
        const int row = t >> 1;
        const float4* Ep = (const float4*)(E + (size_t)(base + row) * DIM + (t & 1) * 32);
#pragma unroll
        for (int ci = 0; ci < 4; ++ci) {
            float4 qa = Ep[2 * ci];
            float4 qb = Ep[2 * ci + 1];
            uint4 u;
            u.x = pack2bf(qa.x, qa.y); u.y = pack2bf(qa.z, qa.w);
            u.z = pack2bf(qb.x, qb.y); u.w = pack2bf(qb.z, qb.w);
            *(uint4*)(bufA + swz(row, (t & 1) * 64 + 16 * ci)) = u;
        }
    }

    short8v w1f0, w1f1, w2f0, w2f1, bwf0, bwf1, cwf0, cwf1;
    LOAD_WF(w1, 0, w1f0); LOAD_WF(w1, 1, w1f1);
    LOAD_WF(w2, 0, w2f0); LOAD_WF(w2, 1, w2f1);
    LOAD_WF(Bw, 0, bwf0); LOAD_WF(Bw, 1, bwf1);
    LOAD_WF(Cw, 0, cwf0); LOAD_WF(Cw, 1, cwf1);
    const float bb1 = b1[col], bb2 = b2[col], bbB = Bb[col], bbC = Cb[col];

    __syncthreads();

    // ---- layer 1: x1 = relu(E @ w1 + b1) : bufA -> bufB ----
#pragma unroll
    for (int mt = 0; mt < 8; ++mt) {
        const int arow = mt * 16 + c;
        short8v a0 = *(const short8v*)(bufA + swz(arow, 16 * g));
        short8v a1 = *(const short8v*)(bufA + swz(arow, 64 + 16 * g));
        f32x4 acc = {0.f, 0.f, 0.f, 0.f};
        acc = __builtin_amdgcn_mfma_f32_16x16x32_bf16(a0, w1f0, acc, 0, 0, 0);
        acc = __builtin_amdgcn_mfma_f32_16x16x32_bf16(a1, w1f1, acc, 0, 0, 0);
#pragma unroll
        for (int r = 0; r < 4; ++r) {
            const float v = fmaxf(acc[r] + bb1, 0.f);
            *(unsigned short*)(bufB + swz(mt * 16 + 4 * g + r, colbyte)) = bfbits(v);
        }
    }
    __syncthreads();

    // ---- layer 2: x2 = relu(x1 @ w2 + b2) : bufB -> bufA ----
#pragma unroll
    for (int mt = 0; mt < 8; ++mt) {
        const int arow = mt * 16 + c;
        short8v a0 = *(const short8v*)(bufB + swz(arow, 16 * g));
        short8v a1 = *(const short8v*)(bufB + swz(arow, 64 + 16 * g));
        f32x4 acc = {0.f, 0.f, 0.f, 0.f};
        acc = __builtin_amdgcn_mfma_f32_16x16x32_bf16(a0, w2f0, acc, 0, 0, 0);
        acc = __builtin_amdgcn_mfma_f32_16x16x32_bf16(a1, w2f1, acc, 0, 0, 0);
#pragma unroll
        for (int r = 0; r < 4; ++r) {
            const float v = fmaxf(acc[r] + bb2, 0.f);
            *(unsigned short*)(bufA + swz(mt * 16 + 4 * g + r, colbyte)) = bfbits(v);
        }
    }
    __syncthreads();

    // ---- gate + shift GEMMs from x2 (bufA) ----
    f32x4 ag[8], as_[8];
#pragma unroll
    for (int mt = 0; mt < 8; ++mt) {
        const int arow = mt * 16 + c;
        short8v a0 = *(const short8v*)(bufA + swz(arow, 16 * g));
        short8v a1 = *(const short8v*)(bufA + swz(arow, 64 + 16 * g));
        f32x4 t0 = {0.f, 0.f, 0.f, 0.f};
        t0 = __builtin_amdgcn_mfma_f32_16x16x32_bf16(a0, bwf0, t0, 0, 0, 0);
        t0 = __builtin_amdgcn_mfma_f32_16x16x32_bf16(a1, bwf1, t0, 0, 0, 0);
        ag[mt] = t0;
        f32x4 t1 = {0.f, 0.f, 0.f, 0.f};
        t1 = __builtin_amdgcn_mfma_f32_16x16x32_bf16(a0, cwf0, t1, 0, 0, 0);
        t1 = __builtin_amdgcn_mfma_f32_16x16x32_bf16(a1, cwf1, t1, 0, 0, 0);
        as_[mt] = t1;
    }

    // ---- gather Vp[src], msg, M = max(msg,EPS)^2 -> bufB ----
#pragma unroll
    for (int mt = 0; mt < 8; ++mt) {
#pragma unroll
        for (int r = 0; r < 4; ++r) {
            const int eloc = mt * 16 + 4 * g + r;
            const int sv = srcv[eloc];
            const float vp = Vp[(size_t)sv * DIM + col];
            const float gate = 1.f / (1.f + __expf(-(ag[mt][r] + bbB)));
            const float sh = as_[mt][r] + bbC;
            float m = fmaf(gate, vp, sh);
            m = fmaxf(m, EPS);
            m = m * m;
            *(unsigned short*)(bufB + swz(eloc, colbyte)) = bfbits(m);
        }
    }
    __syncthreads();

    // ---- copy-out to CSR slot: 2 threads per edge row, 64B each ----
    {
        const int row = t >> 1;
        const int pos = eposv[row];
        uint4 v[4];
#pragma unroll
        for (int ci = 0; ci < 4; ++ci)
            v[ci] = *(const uint4*)(bufB + swz(row, (t & 1) * 64 + 16 * ci));
        uint4* dp = (uint4*)((unsigned short*)msg + (size_t)pos * DIM + (t & 1) * 32);
#pragma unroll
        for (int ci = 0; ci < 4; ++ci) dp[ci] = v[ci];
    }
}

// ---------------------------------------------------------------------------
// Aggregate: one wave per node; 2 edges per trip (dword loads), shfl combine.
// ---------------------------------------------------------------------------
__global__ __launch_bounds__(256) void aggregate_kernel(
    const __hip_bfloat16* __restrict__ msg,
    const int* __restrict__ offs, const int* __restrict__ cnt,
    float* __restrict__ out)
{
    const int n = (blockIdx.x * 256 + threadIdx.x) >> 6;
    const int lane = threadIdx.x & 63;
    if (n >= N_NODES) return;
    const int start = offs[n];
    const int deg = cnt[n];
    const int half = lane >> 5;   // 0: even edge of pair, 1: odd edge
    const int c2 = lane & 31;     // dim-pair index (dims 2c2, 2c2+1)

    const unsigned* base = (const unsigned*)(msg + (size_t)start * DIM);
    float accx = 0.f, accy = 0.f;
    int i = 0;
    for (; i + 4 <= deg; i += 4) {
        const unsigned u0 = base[(size_t)i * 32 + lane];
        const unsigned u1 = base[(size_t)(i + 2) * 32 + lane];
        accx += __uint_as_float(u0 << 16);
        accy += __uint_as_float(u0 & 0xffff0000u);
        accx += __uint_as_float(u1 << 16);
        accy += __uint_as_float(u1 & 0xffff0000u);
    }
    for (; i + 2 <= deg; i += 2) {
        const unsigned u0 = base[(size_t)i * 32 + lane];
        accx += __uint_as_float(u0 << 16);
        accy += __uint_as_float(u0 & 0xffff0000u);
    }
    if (i < deg && half == 0) {
        const unsigned u0 = base[(size_t)i * 32 + c2];
        accx += __uint_as_float(u0 << 16);
        accy += __uint_as_float(u0 & 0xffff0000u);
    }
    // cross-half combine (edge pairs)
    accx += __shfl_xor(accx, 32, 64);
    accy += __shfl_xor(accy, 32, 64);

    if (half == 0) {
        const float dinv = (deg > 0) ? 1.0f / (float)deg : 0.0f;
        float2 o;
        o.x = sqrtf(accx * dinv);
        o.y = sqrtf(accy * dinv);
        *(float2*)(out + (size_t)n * DIM + 2 * c2) = o;
    }
}

extern "C" void kernel_launch(void* const* d_in, const int* in_sizes, int n_in,
                              void* d_out, int out_size, void* d_ws, size_t ws_size,
                              hipStream_t stream) {
    const float* V   = (const float*)d_in[0];
    const float* E   = (const float*)d_in[1];
    const int*   src = (const int*)d_in[2];
    const int*   dst = (const int*)d_in[3];
    const float* w1  = (const float*)d_in[4];
    const float* b1  = (const float*)d_in[5];
    const float* w2  = (const float*)d_in[6];
    const float* b2  = (const float*)d_in[7];
    const float* Bw  = (const float*)d_in[8];
    const float* Bb  = (const float*)d_in[9];
    const float* Cw  = (const float*)d_in[10];
    const float* Cb  = (const float*)d_in[11];
    const float* pAw = (const float*)d_in[12];
    const float* pAb = (const float*)d_in[13];
    const float* pBw = (const float*)d_in[14];
    const float* pBb = (const float*)d_in[15];

    float* out = (float*)d_out;

    // workspace layout
    char* p = (char*)d_ws;
    float* Vp = (float*)p;                    p += (size_t)N_NODES * DIM * sizeof(float);
    __hip_bfloat16* msg = (__hip_bfloat16*)p; p += (size_t)N_EDGES * DIM * 2;
    int* cnt  = (int*)p; p += (size_t)N_NODES * 4;
    int* offs = (int*)p; p += (size_t)N_NODES * 4;
    int* rank = (int*)p; p += (size_t)N_EDGES * 4;

    (void)hipMemsetAsync(cnt, 0, (size_t)N_NODES * sizeof(int), stream);

    node_kernel<<<(N_NODES + 127) / 128, 256, 0, stream>>>(V, pAw, pAb, pBw, pBb, Vp);
    hist_kernel<<<N_EDGES / 256, 256, 0, stream>>>(dst, cnt, rank);
    scan_kernel<<<1, SCAN_T, 0, stream>>>(cnt, offs);
    edge_kernel<<<N_EDGES / 128, 256, 0, stream>>>(E, src, dst, rank, offs,
                                                   w1, b1, w2, b2,
                                                   Bw, Bb, Cw, Cb, Vp, msg);
    aggregate_kernel<<<(N_NODES * 64 + 255) / 256, 256, 0, stream>>>(msg, offs, cnt, out);
}

// Round 6
// 271.411 us; speedup vs baseline: 10.3689x; 1.1461x over previous
//
#include <hip/hip_runtime.h>
#include <hip/hip_bf16.h>
#include <math.h>

// Problem constants (match reference)
#define N_NODES 50000
#define N_EDGES 800000
#define DIM 64
#define NEG_SLOPE 0.2f
#define EPS 1e-5f

typedef __attribute__((ext_vector_type(8))) short short8v;  // 8 bf16 (4 VGPRs)
typedef __attribute__((ext_vector_type(4))) float f32x4;    // MFMA accumulator

__device__ __forceinline__ float lrelu(float v) { return fmaxf(v, NEG_SLOPE * v); }

__device__ __forceinline__ unsigned short bfbits(float v) {
    return __bfloat16_as_ushort(__float2bfloat16(v));
}
// packed pair f32->bf16
__device__ __forceinline__ unsigned pack2bf(float a, float b) {
    union { __hip_bfloat162 h; unsigned u; } cvt;
    cvt.h = __float22bfloat162_rn(make_float2(a, b));
    return cvt.u;
}

// Swizzled byte offset into a 128-byte-stride LDS tile (T2: byte ^= (row&7)<<4).
__device__ __forceinline__ unsigned swz(unsigned row, unsigned byteInRow) {
    return row * 128u + (byteInRow ^ ((row & 7u) << 4));
}

#define LDS_BUF 16384  // 128 rows x 128 bytes

// Fragment-layout weight store: matrix m, entry idx=(ks*4+g)*64+col holds
// short8 {bf16(W[(32ks+8g+j)*64+col]), j=0..7}. One b128 load per fragment.
#define WFRAG_ENTRIES 512   // 2ks * 4g * 64col per matrix

// ---------------------------------------------------------------------------
// prep: convert 6 weight matrices fp32 -> fragment-layout bf16 (once)
// grid = 6 blocks (one per matrix), 256 threads, 2 entries/thread
// ---------------------------------------------------------------------------
__global__ __launch_bounds__(256) void prep_kernel(
    const float* __restrict__ w1, const float* __restrict__ w2,
    const float* __restrict__ Bw, const float* __restrict__ Cw,
    const float* __restrict__ pAw, const float* __restrict__ pBw,
    unsigned short* __restrict__ wbf)
{
    const float* W;
    switch (blockIdx.x) {
        case 0: W = w1; break;
        case 1: W = w2; break;
        case 2: W = Bw; break;
        case 3: W = Cw; break;
        case 4: W = pAw; break;
        default: W = pBw; break;
    }
    const int t = threadIdx.x;
#pragma unroll
    for (int ii = 0; ii < 2; ++ii) {
        const int idx = t * 2 + ii;          // 0..511
        const int ks  = idx >> 8;
        const int g   = (idx >> 6) & 3;
        const int col = idx & 63;
        unsigned short* o = wbf + (size_t)blockIdx.x * 4096 + (size_t)idx * 8;
#pragma unroll
        for (int j = 0; j < 8; ++j)
            o[j] = bfbits(W[(32 * ks + 8 * g + j) * DIM + col]);
    }
}

// fragment fetch helper (m = matrix id, ks = k-step)
__device__ __forceinline__ short8v wfrag(const unsigned short* wbf, int m, int ks,
                                         int g, int col) {
    return ((const short8v*)wbf)[m * WFRAG_ENTRIES + (ks * 4 + g) * 64 + col];
}

// ---------------------------------------------------------------------------
// Node pooling via MFMA: Vp = lrelu(lrelu(V)@pAw+pAb)@pBw+pBb
// ---------------------------------------------------------------------------
__global__ __launch_bounds__(256) void node_kernel(
    const float* __restrict__ V,
    const unsigned short* __restrict__ wbf,
    const float* __restrict__ pAb, const float* __restrict__ pBb,
    float* __restrict__ Vp)
{
    __shared__ __align__(16) unsigned char sm[2 * LDS_BUF];
    unsigned char* bufA = sm;
    unsigned char* bufB = sm + LDS_BUF;

    const int t    = threadIdx.x;
    const int w    = t >> 6;
    const int lane = t & 63;
    const int g    = lane >> 4;
    const int c    = lane & 15;
    const int col  = 16 * w + c;
    const unsigned colbyte = (unsigned)col * 2;
    const int base = blockIdx.x * 128;

    // stage lrelu(V) rows -> bufA (bf16, swizzled); zero-fill past N_NODES
    {
        const int row = t >> 1;
        const int n = base + row;
        if (n < N_NODES) {
            const float4* Vr = (const float4*)(V + (size_t)n * DIM + (t & 1) * 32);
#pragma unroll
            for (int ci = 0; ci < 4; ++ci) {
                float4 qa = Vr[2 * ci];
                float4 qb = Vr[2 * ci + 1];
                uint4 u;
                u.x = pack2bf(lrelu(qa.x), lrelu(qa.y));
                u.y = pack2bf(lrelu(qa.z), lrelu(qa.w));
                u.z = pack2bf(lrelu(qb.x), lrelu(qb.y));
                u.w = pack2bf(lrelu(qb.z), lrelu(qb.w));
                *(uint4*)(bufA + swz(row, (t & 1) * 64 + 16 * ci)) = u;
            }
        } else {
            uint4 z = {0u, 0u, 0u, 0u};
#pragma unroll
            for (int ci = 0; ci < 4; ++ci)
                *(uint4*)(bufA + swz(row, (t & 1) * 64 + 16 * ci)) = z;
        }
    }

    const short8v af0 = wfrag(wbf, 4, 0, g, col), af1 = wfrag(wbf, 4, 1, g, col);
    const short8v bf0 = wfrag(wbf, 5, 0, g, col), bf1 = wfrag(wbf, 5, 1, g, col);
    const float bbA = pAb[col], bbB = pBb[col];

    __syncthreads();

    // layer A: lrelu(x @ pAw + pAb) : bufA -> bufB
#pragma unroll
    for (int mt = 0; mt < 8; ++mt) {
        const int arow = mt * 16 + c;
        short8v a0 = *(const short8v*)(bufA + swz(arow, 16 * g));
        short8v a1 = *(const short8v*)(bufA + swz(arow, 64 + 16 * g));
        f32x4 acc = {0.f, 0.f, 0.f, 0.f};
        acc = __builtin_amdgcn_mfma_f32_16x16x32_bf16(a0, af0, acc, 0, 0, 0);
        acc = __builtin_amdgcn_mfma_f32_16x16x32_bf16(a1, af1, acc, 0, 0, 0);
#pragma unroll
        for (int r = 0; r < 4; ++r) {
            const float v = lrelu(acc[r] + bbA);
            *(unsigned short*)(bufB + swz(mt * 16 + 4 * g + r, colbyte)) = bfbits(v);
        }
    }
    __syncthreads();

    // layer B: x @ pBw + pBb : bufB -> global Vp (fp32)
#pragma unroll
    for (int mt = 0; mt < 8; ++mt) {
        const int arow = mt * 16 + c;
        short8v a0 = *(const short8v*)(bufB + swz(arow, 16 * g));
        short8v a1 = *(const short8v*)(bufB + swz(arow, 64 + 16 * g));
        f32x4 acc = {0.f, 0.f, 0.f, 0.f};
        acc = __builtin_amdgcn_mfma_f32_16x16x32_bf16(a0, bf0, acc, 0, 0, 0);
        acc = __builtin_amdgcn_mfma_f32_16x16x32_bf16(a1, bf1, acc, 0, 0, 0);
#pragma unroll
        for (int r = 0; r < 4; ++r) {
            const int n = base + mt * 16 + 4 * g + r;
            if (n < N_NODES) Vp[(size_t)n * DIM + col] = acc[r] + bbB;
        }
    }
}

// ---------------------------------------------------------------------------
// hist: per-dst count AND per-edge rank (slot within its node)
// ---------------------------------------------------------------------------
__global__ __launch_bounds__(256) void hist_kernel(
    const int* __restrict__ dst, int* __restrict__ cnt, int* __restrict__ rank)
{
    const int e = blockIdx.x * 256 + threadIdx.x;   // 800000 % 256 == 0
    rank[e] = atomicAdd(&cnt[dst[e]], 1);
}

#define SCAN_T 1024
#define SCAN_C 49   // 1024*49 = 50176 >= 50000
__global__ __launch_bounds__(SCAN_T) void scan_kernel(
    const int* __restrict__ cnt, int* __restrict__ offs)
{
    __shared__ int ts[SCAN_T];
    const int t = threadIdx.x;
    const int base = t * SCAN_C;
    int s = 0;
    for (int i = 0; i < SCAN_C; ++i) {
        const int idx = base + i;
        s += (idx < N_NODES) ? cnt[idx] : 0;
    }
    ts[t] = s;
    __syncthreads();
    for (int off = 1; off < SCAN_T; off <<= 1) {
        const int add = (t >= off) ? ts[t - off] : 0;
        __syncthreads();
        ts[t] += add;
        __syncthreads();
    }
    int run = (t == 0) ? 0 : ts[t - 1];
    for (int i = 0; i < SCAN_C; ++i) {
        const int idx = base + i;
        if (idx < N_NODES) { offs[idx] = run; run += cnt[idx]; }
    }
}

// ---------------------------------------------------------------------------
// MFMA edge pipeline. Block = 128 edges, 256 threads = 4 waves.
// Weights from fragment-layout bf16 (1 b128 load each); Vp gather prefetched
// into registers at kernel start; gate/shift GEMM fused with message phase.
// ---------------------------------------------------------------------------
__global__ __launch_bounds__(256) void edge_kernel(
    const float* __restrict__ E,
    const int* __restrict__ src, const int* __restrict__ dst,
    const int* __restrict__ rank, const int* __restrict__ offs,
    const unsigned short* __restrict__ wbf,
    const float* __restrict__ b1, const float* __restrict__ b2,
    const float* __restrict__ Bb, const float* __restrict__ Cb,
    const float* __restrict__ Vp,
    __hip_bfloat16* __restrict__ msg)
{
    __shared__ __align__(16) unsigned char sm[2 * LDS_BUF + 128 * 4];
    unsigned char* bufA = sm;
    unsigned char* bufB = sm + LDS_BUF;
    int* eposv = (int*)(sm + 2 * LDS_BUF);

    const int t    = threadIdx.x;
    const int w    = t >> 6;
    const int lane = t & 63;
    const int g    = lane >> 4;
    const int c    = lane & 15;
    const int col  = 16 * w + c;
    const unsigned colbyte = (unsigned)col * 2;
    const int base = blockIdx.x * 128;

    // ---- Vp gather prefetch: 32 independent chains, in flight during GEMMs
    float vpre[32];
#pragma unroll
    for (int mt = 0; mt < 8; ++mt) {
#pragma unroll
        for (int r = 0; r < 4; ++r) {
            const int sv = src[base + mt * 16 + 4 * g + r];
            vpre[mt * 4 + r] = Vp[(size_t)sv * DIM + col];
        }
    }

    // ---- CSR slot for copy-out ----
    if (t < 128) eposv[t] = offs[dst[base + t]] + rank[base + t];

    // ---- stage E tile (fp32 -> bf16, swizzled) ----
    {
        const int row = t >> 1;
        const float4* Ep = (const float4*)(E + (size_t)(base + row) * DIM + (t & 1) * 32);
#pragma unroll
        for (int ci = 0; ci < 4; ++ci) {
            float4 qa = Ep[2 * ci];
            float4 qb = Ep[2 * ci + 1];
            uint4 u;
            u.x = pack2bf(qa.x, qa.y); u.y = pack2bf(qa.z, qa.w);
            u.z = pack2bf(qb.x, qb.y); u.w = pack2bf(qb.z, qb.w);
            *(uint4*)(bufA + swz(row, (t & 1) * 64 + 16 * ci)) = u;
        }
    }

    // ---- weight fragments: one b128 load each ----
    const short8v w1f0 = wfrag(wbf, 0, 0, g, col), w1f1 = wfrag(wbf, 0, 1, g, col);
    const short8v w2f0 = wfrag(wbf, 1, 0, g, col), w2f1 = wfrag(wbf, 1, 1, g, col);
    const short8v bwf0 = wfrag(wbf, 2, 0, g, col), bwf1 = wfrag(wbf, 2, 1, g, col);
    const short8v cwf0 = wfrag(wbf, 3, 0, g, col), cwf1 = wfrag(wbf, 3, 1, g, col);
    const float bb1 = b1[col], bb2 = b2[col], bbB = Bb[col], bbC = Cb[col];

    __syncthreads();

    // ---- layer 1: x1 = relu(E @ w1 + b1) : bufA -> bufB ----
#pragma unroll
    for (int mt = 0; mt < 8; ++mt) {
        const int arow = mt * 16 + c;
        short8v a0 = *(const short8v*)(bufA + swz(arow, 16 * g));
        short8v a1 = *(const short8v*)(bufA + swz(arow, 64 + 16 * g));
        f32x4 acc = {0.f, 0.f, 0.f, 0.f};
        acc = __builtin_amdgcn_mfma_f32_16x16x32_bf16(a0, w1f0, acc, 0, 0, 0);
        acc = __builtin_amdgcn_mfma_f32_16x16x32_bf16(a1, w1f1, acc, 0, 0, 0);
#pragma unroll
        for (int r = 0; r < 4; ++r) {
            const float v = fmaxf(acc[r] + bb1, 0.f);
            *(unsigned short*)(bufB + swz(mt * 16 + 4 * g + r, colbyte)) = bfbits(v);
        }
    }
    __syncthreads();

    // ---- layer 2: x2 = relu(x1 @ w2 + b2) : bufB -> bufA ----
#pragma unroll
    for (int mt = 0; mt < 8; ++mt) {
        const int arow = mt * 16 + c;
        short8v a0 = *(const short8v*)(bufB + swz(arow, 16 * g));
        short8v a1 = *(const short8v*)(bufB + swz(arow, 64 + 16 * g));
        f32x4 acc = {0.f, 0.f, 0.f, 0.f};
        acc = __builtin_amdgcn_mfma_f32_16x16x32_bf16(a0, w2f0, acc, 0, 0, 0);
        acc = __builtin_amdgcn_mfma_f32_16x16x32_bf16(a1, w2f1, acc, 0, 0, 0);
#pragma unroll
        for (int r = 0; r < 4; ++r) {
            const float v = fmaxf(acc[r] + bb2, 0.f);
            *(unsigned short*)(bufA + swz(mt * 16 + 4 * g + r, colbyte)) = bfbits(v);
        }
    }
    __syncthreads();

    // ---- gate + shift GEMMs fused with message: bufA(x2) -> bufB(msg) ----
#pragma unroll
    for (int mt = 0; mt < 8; ++mt) {
        const int arow = mt * 16 + c;
        short8v a0 = *(const short8v*)(bufA + swz(arow, 16 * g));
        short8v a1 = *(const short8v*)(bufA + swz(arow, 64 + 16 * g));
        f32x4 t0 = {0.f, 0.f, 0.f, 0.f};
        t0 = __builtin_amdgcn_mfma_f32_16x16x32_bf16(a0, bwf0, t0, 0, 0, 0);
        t0 = __builtin_amdgcn_mfma_f32_16x16x32_bf16(a1, bwf1, t0, 0, 0, 0);
        f32x4 t1 = {0.f, 0.f, 0.f, 0.f};
        t1 = __builtin_amdgcn_mfma_f32_16x16x32_bf16(a0, cwf0, t1, 0, 0, 0);
        t1 = __builtin_amdgcn_mfma_f32_16x16x32_bf16(a1, cwf1, t1, 0, 0, 0);
#pragma unroll
        for (int r = 0; r < 4; ++r) {
            const float gate = 1.f / (1.f + __expf(-(t0[r] + bbB)));
            const float sh = t1[r] + bbC;
            float m = fmaf(gate, vpre[mt * 4 + r], sh);
            m = fmaxf(m, EPS);
            m = m * m;
            *(unsigned short*)(bufB + swz(mt * 16 + 4 * g + r, colbyte)) = bfbits(m);
        }
    }
    __syncthreads();

    // ---- copy-out to CSR slot: 2 threads per edge row, 64B each ----
    {
        const int row = t >> 1;
        const int pos = eposv[row];
        uint4 v[4];
#pragma unroll
        for (int ci = 0; ci < 4; ++ci)
            v[ci] = *(const uint4*)(bufB + swz(row, (t & 1) * 64 + 16 * ci));
        uint4* dp = (uint4*)((unsigned short*)msg + (size_t)pos * DIM + (t & 1) * 32);
#pragma unroll
        for (int ci = 0; ci < 4; ++ci) dp[ci] = v[ci];
    }
}

// ---------------------------------------------------------------------------
// Aggregate: one wave per node; 2 edges per trip (dword loads), shfl combine.
// ---------------------------------------------------------------------------
__global__ __launch_bounds__(256) void aggregate_kernel(
    const __hip_bfloat16* __restrict__ msg,
    const int* __restrict__ offs, const int* __restrict__ cnt,
    float* __restrict__ out)
{
    const int n = (blockIdx.x * 256 + threadIdx.x) >> 6;
    const int lane = threadIdx.x & 63;
    if (n >= N_NODES) return;
    const int start = offs[n];
    const int deg = cnt[n];
    const int half = lane >> 5;   // 0: even edge of pair, 1: odd edge
    const int c2 = lane & 31;     // dim-pair index (dims 2c2, 2c2+1)

    const unsigned* base = (const unsigned*)(msg + (size_t)start * DIM);
    float accx = 0.f, accy = 0.f;
    int i = 0;
    for (; i + 4 <= deg; i += 4) {
        const unsigned u0 = base[(size_t)i * 32 + lane];
        const unsigned u1 = base[(size_t)(i + 2) * 32 + lane];
        accx += __uint_as_float(u0 << 16);
        accy += __uint_as_float(u0 & 0xffff0000u);
        accx += __uint_as_float(u1 << 16);
        accy += __uint_as_float(u1 & 0xffff0000u);
    }
    for (; i + 2 <= deg; i += 2) {
        const unsigned u0 = base[(size_t)i * 32 + lane];
        accx += __uint_as_float(u0 << 16);
        accy += __uint_as_float(u0 & 0xffff0000u);
    }
    if (i < deg && half == 0) {
        const unsigned u0 = base[(size_t)i * 32 + c2];
        accx += __uint_as_float(u0 << 16);
        accy += __uint_as_float(u0 & 0xffff0000u);
    }
    // cross-half combine (edge pairs)
    accx += __shfl_xor(accx, 32, 64);
    accy += __shfl_xor(accy, 32, 64);

    if (half == 0) {
        const float dinv = (deg > 0) ? 1.0f / (float)deg : 0.0f;
        float2 o;
        o.x = sqrtf(accx * dinv);
        o.y = sqrtf(accy * dinv);
        *(float2*)(out + (size_t)n * DIM + 2 * c2) = o;
    }
}

extern "C" void kernel_launch(void* const* d_in, const int* in_sizes, int n_in,
                              void* d_out, int out_size, void* d_ws, size_t ws_size,
                              hipStream_t stream) {
    const float* V   = (const float*)d_in[0];
    const float* E   = (const float*)d_in[1];
    const int*   src = (const int*)d_in[2];
    const int*   dst = (const int*)d_in[3];
    const float* w1  = (const float*)d_in[4];
    const float* b1  = (const float*)d_in[5];
    const float* w2  = (const float*)d_in[6];
    const float* b2  = (const float*)d_in[7];
    const float* Bw  = (const float*)d_in[8];
    const float* Bb  = (const float*)d_in[9];
    const float* Cw  = (const float*)d_in[10];
    const float* Cb  = (const float*)d_in[11];
    const float* pAw = (const float*)d_in[12];
    const float* pAb = (const float*)d_in[13];
    const float* pBw = (const float*)d_in[14];
    const float* pBb = (const float*)d_in[15];

    float* out = (float*)d_out;

    // workspace layout
    char* p = (char*)d_ws;
    float* Vp = (float*)p;                    p += (size_t)N_NODES * DIM * sizeof(float);
    __hip_bfloat16* msg = (__hip_bfloat16*)p; p += (size_t)N_EDGES * DIM * 2;
    int* cnt  = (int*)p; p += (size_t)N_NODES * 4;
    int* offs = (int*)p; p += (size_t)N_NODES * 4;
    int* rank = (int*)p; p += (size_t)N_EDGES * 4;
    unsigned short* wbf = (unsigned short*)p; p += (size_t)6 * 4096 * 2;

    (void)hipMemsetAsync(cnt, 0, (size_t)N_NODES * sizeof(int), stream);

    prep_kernel<<<6, 256, 0, stream>>>(w1, w2, Bw, Cw, pAw, pBw, wbf);
    node_kernel<<<(N_NODES + 127) / 128, 256, 0, stream>>>(V, wbf, pAb, pBb, Vp);
    hist_kernel<<<N_EDGES / 256, 256, 0, stream>>>(dst, cnt, rank);
    scan_kernel<<<1, SCAN_T, 0, stream>>>(cnt, offs);
    edge_kernel<<<N_EDGES / 128, 256, 0, stream>>>(E, src, dst, rank, offs, wbf,
                                                   b1, b2, Bb, Cb, Vp, msg);
    aggregate_kernel<<<(N_NODES * 64 + 255) / 256, 256, 0, stream>>>(msg, offs, cnt, out);
}

// Round 7
// 196.031 us; speedup vs baseline: 14.3560x; 1.3845x over previous
//
#include <hip/hip_runtime.h>
#include <hip/hip_bf16.h>
#include <math.h>

// Problem constants (match reference)
#define N_NODES 50000
#define N_EDGES 800000
#define DIM 64
#define NEG_SLOPE 0.2f
#define EPS 1e-5f

typedef __attribute__((ext_vector_type(8))) short short8v;  // 8 bf16 (4 VGPRs)
typedef __attribute__((ext_vector_type(4))) float f32x4;    // MFMA accumulator

__device__ __forceinline__ float lrelu(float v) { return fmaxf(v, NEG_SLOPE * v); }

__device__ __forceinline__ unsigned short bfbits(float v) {
    return __bfloat16_as_ushort(__float2bfloat16(v));
}
// packed pair f32->bf16
__device__ __forceinline__ unsigned pack2bf(float a, float b) {
    union { __hip_bfloat162 h; unsigned u; } cvt;
    cvt.h = __float22bfloat162_rn(make_float2(a, b));
    return cvt.u;
}

// Swizzled byte offset into a 128-byte-stride LDS tile (T2: byte ^= (row&7)<<4).
__device__ __forceinline__ unsigned swz(unsigned row, unsigned byteInRow) {
    return row * 128u + (byteInRow ^ ((row & 7u) << 4));
}

#define LDS_BUF 16384  // 128 rows x 128 bytes

// Fragment-layout weight store: matrix m, entry idx=(ks*4+g)*64+col holds
// short8 {bf16(W[(32ks+8g+j)*64+col]), j=0..7}. One b128 load per fragment.
#define WFRAG_ENTRIES 512   // 2ks * 4g * 64col per matrix

#define SCANA_BLOCKS 49     // 49*1024 = 50176 >= 50000

// ---------------------------------------------------------------------------
// prep: blocks 0..5 convert weight matrices fp32 -> fragment bf16;
//       blocks 6..54 zero cnt (absorbs the memset dispatch)
// ---------------------------------------------------------------------------
__global__ __launch_bounds__(256) void prep_kernel(
    const float* __restrict__ w1, const float* __restrict__ w2,
    const float* __restrict__ Bw, const float* __restrict__ Cw,
    const float* __restrict__ pAw, const float* __restrict__ pBw,
    unsigned short* __restrict__ wbf, int* __restrict__ cnt)
{
    const int t = threadIdx.x;
    if (blockIdx.x >= 6) {
        const int idx = (blockIdx.x - 6) * 1024 + t * 4;
        if (idx + 3 < N_NODES) {
            int4 z = {0, 0, 0, 0};
            *(int4*)(cnt + idx) = z;
        } else {
#pragma unroll
            for (int i = 0; i < 4; ++i)
                if (idx + i < N_NODES) cnt[idx + i] = 0;
        }
        return;
    }
    const float* W;
    switch (blockIdx.x) {
        case 0: W = w1; break;
        case 1: W = w2; break;
        case 2: W = Bw; break;
        case 3: W = Cw; break;
        case 4: W = pAw; break;
        default: W = pBw; break;
    }
#pragma unroll
    for (int ii = 0; ii < 2; ++ii) {
        const int idx = t * 2 + ii;          // 0..511
        const int ks  = idx >> 8;
        const int g   = (idx >> 6) & 3;
        const int col = idx & 63;
        unsigned short* o = wbf + (size_t)blockIdx.x * 4096 + (size_t)idx * 8;
#pragma unroll
        for (int j = 0; j < 8; ++j)
            o[j] = bfbits(W[(32 * ks + 8 * g + j) * DIM + col]);
    }
}

// fragment fetch helper (m = matrix id, ks = k-step)
__device__ __forceinline__ short8v wfrag(const unsigned short* wbf, int m, int ks,
                                         int g, int col) {
    return ((const short8v*)wbf)[m * WFRAG_ENTRIES + (ks * 4 + g) * 64 + col];
}

// ---------------------------------------------------------------------------
// Node pooling via MFMA: Vp = lrelu(lrelu(V)@pAw+pAb)@pBw+pBb
// ---------------------------------------------------------------------------
__global__ __launch_bounds__(256) void node_kernel(
    const float* __restrict__ V,
    const unsigned short* __restrict__ wbf,
    const float* __restrict__ pAb, const float* __restrict__ pBb,
    float* __restrict__ Vp)
{
    __shared__ __align__(16) unsigned char sm[2 * LDS_BUF];
    unsigned char* bufA = sm;
    unsigned char* bufB = sm + LDS_BUF;

    const int t    = threadIdx.x;
    const int w    = t >> 6;
    const int lane = t & 63;
    const int g    = lane >> 4;
    const int c    = lane & 15;
    const int col  = 16 * w + c;
    const unsigned colbyte = (unsigned)col * 2;
    const int base = blockIdx.x * 128;

    // stage lrelu(V) rows -> bufA (bf16, swizzled); zero-fill past N_NODES
    {
        const int row = t >> 1;
        const int n = base + row;
        if (n < N_NODES) {
            const float4* Vr = (const float4*)(V + (size_t)n * DIM + (t & 1) * 32);
#pragma unroll
            for (int ci = 0; ci < 4; ++ci) {
                float4 qa = Vr[2 * ci];
                float4 qb = Vr[2 * ci + 1];
                uint4 u;
                u.x = pack2bf(lrelu(qa.x), lrelu(qa.y));
                u.y = pack2bf(lrelu(qa.z), lrelu(qa.w));
                u.z = pack2bf(lrelu(qb.x), lrelu(qb.y));
                u.w = pack2bf(lrelu(qb.z), lrelu(qb.w));
                *(uint4*)(bufA + swz(row, (t & 1) * 64 + 16 * ci)) = u;
            }
        } else {
            uint4 z = {0u, 0u, 0u, 0u};
#pragma unroll
            for (int ci = 0; ci < 4; ++ci)
                *(uint4*)(bufA + swz(row, (t & 1) * 64 + 16 * ci)) = z;
        }
    }

    const short8v af0 = wfrag(wbf, 4, 0, g, col), af1 = wfrag(wbf, 4, 1, g, col);
    const short8v bf0 = wfrag(wbf, 5, 0, g, col), bf1 = wfrag(wbf, 5, 1, g, col);
    const float bbA = pAb[col], bbB = pBb[col];

    __syncthreads();

    // layer A: lrelu(x @ pAw + pAb) : bufA -> bufB
#pragma unroll
    for (int mt = 0; mt < 8; ++mt) {
        const int arow = mt * 16 + c;
        short8v a0 = *(const short8v*)(bufA + swz(arow, 16 * g));
        short8v a1 = *(const short8v*)(bufA + swz(arow, 64 + 16 * g));
        f32x4 acc = {0.f, 0.f, 0.f, 0.f};
        acc = __builtin_amdgcn_mfma_f32_16x16x32_bf16(a0, af0, acc, 0, 0, 0);
        acc = __builtin_amdgcn_mfma_f32_16x16x32_bf16(a1, af1, acc, 0, 0, 0);
#pragma unroll
        for (int r = 0; r < 4; ++r) {
            const float v = lrelu(acc[r] + bbA);
            *(unsigned short*)(bufB + swz(mt * 16 + 4 * g + r, colbyte)) = bfbits(v);
        }
    }
    __syncthreads();

    // layer B: x @ pBw + pBb : bufB -> global Vp (fp32)
#pragma unroll
    for (int mt = 0; mt < 8; ++mt) {
        const int arow = mt * 16 + c;
        short8v a0 = *(const short8v*)(bufB + swz(arow, 16 * g));
        short8v a1 = *(const short8v*)(bufB + swz(arow, 64 + 16 * g));
        f32x4 acc = {0.f, 0.f, 0.f, 0.f};
        acc = __builtin_amdgcn_mfma_f32_16x16x32_bf16(a0, bf0, acc, 0, 0, 0);
        acc = __builtin_amdgcn_mfma_f32_16x16x32_bf16(a1, bf1, acc, 0, 0, 0);
#pragma unroll
        for (int r = 0; r < 4; ++r) {
            const int n = base + mt * 16 + 4 * g + r;
            if (n < N_NODES) Vp[(size_t)n * DIM + col] = acc[r] + bbB;
        }
    }
}

// ---------------------------------------------------------------------------
// hist: per-dst count AND per-edge rank (slot within its node)
// ---------------------------------------------------------------------------
__global__ __launch_bounds__(256) void hist_kernel(
    const int* __restrict__ dst, int* __restrict__ cnt, int* __restrict__ rank)
{
    const int e = blockIdx.x * 256 + threadIdx.x;   // 800000 % 256 == 0
    rank[e] = atomicAdd(&cnt[dst[e]], 1);
}

// ---------------------------------------------------------------------------
// two-level scan: scanA = per-1024-node block exclusive scan (lofs) + total;
//                 scanB = 1-wave exclusive scan of 49 block totals (bbase)
// consumers compute offs[n] = lofs[n] + bbase[n>>10]
// ---------------------------------------------------------------------------
__global__ __launch_bounds__(256) void scanA_kernel(
    const int* __restrict__ cnt, int* __restrict__ lofs, int* __restrict__ btot)
{
    __shared__ int ts[256];
    const int t = threadIdx.x;
    const int nb = blockIdx.x * 1024 + t * 4;
    int4 c = {0, 0, 0, 0};
    if (nb + 3 < N_NODES) {
        c = *(const int4*)(cnt + nb);
    } else {
        if (nb + 0 < N_NODES) c.x = cnt[nb + 0];
        if (nb + 1 < N_NODES) c.y = cnt[nb + 1];
        if (nb + 2 < N_NODES) c.z = cnt[nb + 2];
        if (nb + 3 < N_NODES) c.w = cnt[nb + 3];
    }
    ts[t] = c.x + c.y + c.z + c.w;
    __syncthreads();
    for (int off = 1; off < 256; off <<= 1) {
        const int add = (t >= off) ? ts[t - off] : 0;
        __syncthreads();
        ts[t] += add;
        __syncthreads();
    }
    int4 o;
    o.x = (t == 0) ? 0 : ts[t - 1];
    o.y = o.x + c.x;
    o.z = o.y + c.y;
    o.w = o.z + c.z;
    if (nb + 3 < N_NODES) {
        *(int4*)(lofs + nb) = o;
    } else {
        if (nb + 0 < N_NODES) lofs[nb + 0] = o.x;
        if (nb + 1 < N_NODES) lofs[nb + 1] = o.y;
        if (nb + 2 < N_NODES) lofs[nb + 2] = o.z;
        if (nb + 3 < N_NODES) lofs[nb + 3] = o.w;
    }
    if (t == 255) btot[blockIdx.x] = ts[255];
}

__global__ __launch_bounds__(64) void scanB_kernel(
    const int* __restrict__ btot, int* __restrict__ bbase)
{
    const int t = threadIdx.x;    // one wave
    const int own = (t < SCANA_BLOCKS) ? btot[t] : 0;
    int v = own;
    for (int off = 1; off < 64; off <<= 1) {
        const int u = __shfl_up(v, off, 64);
        if (t >= off) v += u;
    }
    if (t < SCANA_BLOCKS) bbase[t] = v - own;   // exclusive
}

// ---------------------------------------------------------------------------
// MFMA edge pipeline. Block = 128 edges, 256 threads = 4 waves.
// LDS exactly 32768 B -> 5 blocks/CU. CSR slot computed into registers.
// ---------------------------------------------------------------------------
__global__ __launch_bounds__(256) void edge_kernel(
    const float* __restrict__ E,
    const int* __restrict__ src, const int* __restrict__ dst,
    const int* __restrict__ rank,
    const int* __restrict__ lofs, const int* __restrict__ bbase,
    const unsigned short* __restrict__ wbf,
    const float* __restrict__ b1, const float* __restrict__ b2,
    const float* __restrict__ Bb, const float* __restrict__ Cb,
    const float* __restrict__ Vp,
    __hip_bfloat16* __restrict__ msg)
{
    __shared__ __align__(16) unsigned char sm[2 * LDS_BUF];   // exactly 32 KiB
    unsigned char* bufA = sm;
    unsigned char* bufB = sm + LDS_BUF;

    const int t    = threadIdx.x;
    const int w    = t >> 6;
    const int lane = t & 63;
    const int g    = lane >> 4;
    const int c    = lane & 15;
    const int col  = 16 * w + c;
    const unsigned colbyte = (unsigned)col * 2;
    const int base = blockIdx.x * 128;

    // ---- CSR slot for this thread's copy-out row (registers, used at end)
    const int myrow = t >> 1;
    const int d_my = dst[base + myrow];
    const int pos = lofs[d_my] + bbase[d_my >> 10] + rank[base + myrow];

    // ---- Vp gather prefetch: 32 independent chains, in flight during GEMMs
    float vpre[32];
#pragma unroll
    for (int mt = 0; mt < 8; ++mt) {
#pragma unroll
        for (int r = 0; r < 4; ++r) {
            const int sv = src[base + mt * 16 + 4 * g + r];
            vpre[mt * 4 + r] = Vp[(size_t)sv * DIM + col];
        }
    }

    // ---- stage E tile (fp32 -> bf16, swizzled) ----
    {
        const float4* Ep = (const float4*)(E + (size_t)(base + myrow) * DIM + (t & 1) * 32);
#pragma unroll
        for (int ci = 0; ci < 4; ++ci) {
            float4 qa = Ep[2 * ci];
            float4 qb = Ep[2 * ci + 1];
            uint4 u;
            u.x = pack2bf(qa.x, qa.y); u.y = pack2bf(qa.z, qa.w);
            u.z = pack2bf(qb.x, qb.y); u.w = pack2bf(qb.z, qb.w);
            *(uint4*)(bufA + swz(myrow, (t & 1) * 64 + 16 * ci)) = u;
        }
    }

    // ---- weight fragments: one b128 load each ----
    const short8v w1f0 = wfrag(wbf, 0, 0, g, col), w1f1 = wfrag(wbf, 0, 1, g, col);
    const short8v w2f0 = wfrag(wbf, 1, 0, g, col), w2f1 = wfrag(wbf, 1, 1, g, col);
    const short8v bwf0 = wfrag(wbf, 2, 0, g, col), bwf1 = wfrag(wbf, 2, 1, g, col);
    const short8v cwf0 = wfrag(wbf, 3, 0, g, col), cwf1 = wfrag(wbf, 3, 1, g, col);
    const float bb1 = b1[col], bb2 = b2[col], bbB = Bb[col], bbC = Cb[col];

    __syncthreads();

    // ---- layer 1: x1 = relu(E @ w1 + b1) : bufA -> bufB ----
#pragma unroll
    for (int mt = 0; mt < 8; ++mt) {
        const int arow = mt * 16 + c;
        short8v a0 = *(const short8v*)(bufA + swz(arow, 16 * g));
        short8v a1 = *(const short8v*)(bufA + swz(arow, 64 + 16 * g));
        f32x4 acc = {0.f, 0.f, 0.f, 0.f};
        acc = __builtin_amdgcn_mfma_f32_16x16x32_bf16(a0, w1f0, acc, 0, 0, 0);
        acc = __builtin_amdgcn_mfma_f32_16x16x32_bf16(a1, w1f1, acc, 0, 0, 0);
#pragma unroll
        for (int r = 0; r < 4; ++r) {
            const float v = fmaxf(acc[r] + bb1, 0.f);
            *(unsigned short*)(bufB + swz(mt * 16 + 4 * g + r, colbyte)) = bfbits(v);
        }
    }
    __syncthreads();

    // ---- layer 2: x2 = relu(x1 @ w2 + b2) : bufB -> bufA ----
#pragma unroll
    for (int mt = 0; mt < 8; ++mt) {
        const int arow = mt * 16 + c;
        short8v a0 = *(const short8v*)(bufB + swz(arow, 16 * g));
        short8v a1 = *(const short8v*)(bufB + swz(arow, 64 + 16 * g));
        f32x4 acc = {0.f, 0.f, 0.f, 0.f};
        acc = __builtin_amdgcn_mfma_f32_16x16x32_bf16(a0, w2f0, acc, 0, 0, 0);
        acc = __builtin_amdgcn_mfma_f32_16x16x32_bf16(a1, w2f1, acc, 0, 0, 0);
#pragma unroll
        for (int r = 0; r < 4; ++r) {
            const float v = fmaxf(acc[r] + bb2, 0.f);
            *(unsigned short*)(bufA + swz(mt * 16 + 4 * g + r, colbyte)) = bfbits(v);
        }
    }
    __syncthreads();

    // ---- gate + shift GEMMs fused with message: bufA(x2) -> bufB(msg) ----
#pragma unroll
    for (int mt = 0; mt < 8; ++mt) {
        const int arow = mt * 16 + c;
        short8v a0 = *(const short8v*)(bufA + swz(arow, 16 * g));
        short8v a1 = *(const short8v*)(bufA + swz(arow, 64 + 16 * g));
        f32x4 t0 = {0.f, 0.f, 0.f, 0.f};
        t0 = __builtin_amdgcn_mfma_f32_16x16x32_bf16(a0, bwf0, t0, 0, 0, 0);
        t0 = __builtin_amdgcn_mfma_f32_16x16x32_bf16(a1, bwf1, t0, 0, 0, 0);
        f32x4 t1 = {0.f, 0.f, 0.f, 0.f};
        t1 = __builtin_amdgcn_mfma_f32_16x16x32_bf16(a0, cwf0, t1, 0, 0, 0);
        t1 = __builtin_amdgcn_mfma_f32_16x16x32_bf16(a1, cwf1, t1, 0, 0, 0);
#pragma unroll
        for (int r = 0; r < 4; ++r) {
            const float gate = 1.f / (1.f + __expf(-(t0[r] + bbB)));
            const float sh = t1[r] + bbC;
            float m = fmaf(gate, vpre[mt * 4 + r], sh);
            m = fmaxf(m, EPS);
            m = m * m;
            *(unsigned short*)(bufB + swz(mt * 16 + 4 * g + r, colbyte)) = bfbits(m);
        }
    }
    __syncthreads();

    // ---- copy-out to CSR slot: 2 threads per edge row, 64B each ----
    {
        uint4 v[4];
#pragma unroll
        for (int ci = 0; ci < 4; ++ci)
            v[ci] = *(const uint4*)(bufB + swz(myrow, (t & 1) * 64 + 16 * ci));
        uint4* dp = (uint4*)((unsigned short*)msg + (size_t)pos * DIM + (t & 1) * 32);
#pragma unroll
        for (int ci = 0; ci < 4; ++ci) dp[ci] = v[ci];
    }
}

// ---------------------------------------------------------------------------
// Aggregate: one wave per node; 8 edges per trip via uint4 (full 128B rows,
// 1KB coalesced per wave-trip); 3-round shfl_xor cross-row reduction.
// ---------------------------------------------------------------------------
__global__ __launch_bounds__(256) void aggregate_kernel(
    const __hip_bfloat16* __restrict__ msg,
    const int* __restrict__ lofs, const int* __restrict__ bbase,
    const int* __restrict__ cnt,
    float* __restrict__ out)
{
    const int n = (blockIdx.x * 256 + threadIdx.x) >> 6;
    const int lane = threadIdx.x & 63;
    if (n >= N_NODES) return;
    const int start = lofs[n] + bbase[n >> 10];
    const int deg = cnt[n];
    const int rowg = lane >> 3;   // which of 8 rows in the trip
    const int dblk = lane & 7;    // dims [8*dblk, 8*dblk+8)

    const unsigned short* bp = (const unsigned short*)msg + (size_t)start * DIM + dblk * 8;
    float acc0 = 0.f, acc1 = 0.f, acc2 = 0.f, acc3 = 0.f;
    float acc4 = 0.f, acc5 = 0.f, acc6 = 0.f, acc7 = 0.f;
    for (int i = 0; i < deg; i += 8) {
        const int r = i + rowg;
        if (r < deg) {
            const uint4 u = *(const uint4*)(bp + (size_t)r * DIM);
            acc0 += __uint_as_float(u.x << 16);
            acc1 += __uint_as_float(u.x & 0xffff0000u);
            acc2 += __uint_as_float(u.y << 16);
            acc3 += __uint_as_float(u.y & 0xffff0000u);
            acc4 += __uint_as_float(u.z << 16);
            acc5 += __uint_as_float(u.z & 0xffff0000u);
            acc6 += __uint_as_float(u.w << 16);
            acc7 += __uint_as_float(u.w & 0xffff0000u);
        }
    }
    // reduce across the 8 row-groups (partners share dblk)
#pragma unroll
    for (int m = 8; m <= 32; m <<= 1) {
        acc0 += __shfl_xor(acc0, m, 64);
        acc1 += __shfl_xor(acc1, m, 64);
        acc2 += __shfl_xor(acc2, m, 64);
        acc3 += __shfl_xor(acc3, m, 64);
        acc4 += __shfl_xor(acc4, m, 64);
        acc5 += __shfl_xor(acc5, m, 64);
        acc6 += __shfl_xor(acc6, m, 64);
        acc7 += __shfl_xor(acc7, m, 64);
    }
    if (rowg == 0) {
        const float dinv = (deg > 0) ? 1.0f / (float)deg : 0.0f;
        float4 o0, o1;
        o0.x = sqrtf(acc0 * dinv); o0.y = sqrtf(acc1 * dinv);
        o0.z = sqrtf(acc2 * dinv); o0.w = sqrtf(acc3 * dinv);
        o1.x = sqrtf(acc4 * dinv); o1.y = sqrtf(acc5 * dinv);
        o1.z = sqrtf(acc6 * dinv); o1.w = sqrtf(acc7 * dinv);
        float4* op = (float4*)(out + (size_t)n * DIM + dblk * 8);
        op[0] = o0;
        op[1] = o1;
    }
}

extern "C" void kernel_launch(void* const* d_in, const int* in_sizes, int n_in,
                              void* d_out, int out_size, void* d_ws, size_t ws_size,
                              hipStream_t stream) {
    const float* V   = (const float*)d_in[0];
    const float* E   = (const float*)d_in[1];
    const int*   src = (const int*)d_in[2];
    const int*   dst = (const int*)d_in[3];
    const float* w1  = (const float*)d_in[4];
    const float* b1  = (const float*)d_in[5];
    const float* w2  = (const float*)d_in[6];
    const float* b2  = (const float*)d_in[7];
    const float* Bw  = (const float*)d_in[8];
    const float* Bb  = (const float*)d_in[9];
    const float* Cw  = (const float*)d_in[10];
    const float* Cb  = (const float*)d_in[11];
    const float* pAw = (const float*)d_in[12];
    const float* pAb = (const float*)d_in[13];
    const float* pBw = (const float*)d_in[14];
    const float* pBb = (const float*)d_in[15];

    float* out = (float*)d_out;

    // workspace layout
    char* p = (char*)d_ws;
    float* Vp = (float*)p;                    p += (size_t)N_NODES * DIM * sizeof(float);
    __hip_bfloat16* msg = (__hip_bfloat16*)p; p += (size_t)N_EDGES * DIM * 2;
    int* cnt  = (int*)p; p += (size_t)50176 * 4;
    int* lofs = (int*)p; p += (size_t)50176 * 4;
    int* rank = (int*)p; p += (size_t)N_EDGES * 4;
    unsigned short* wbf = (unsigned short*)p; p += (size_t)6 * 4096 * 2;
    int* btot  = (int*)p; p += (size_t)64 * 4;
    int* bbase = (int*)p; p += (size_t)64 * 4;

    prep_kernel<<<6 + SCANA_BLOCKS, 256, 0, stream>>>(w1, w2, Bw, Cw, pAw, pBw, wbf, cnt);
    hist_kernel<<<N_EDGES / 256, 256, 0, stream>>>(dst, cnt, rank);
    node_kernel<<<(N_NODES + 127) / 128, 256, 0, stream>>>(V, wbf, pAb, pBb, Vp);
    scanA_kernel<<<SCANA_BLOCKS, 256, 0, stream>>>(cnt, lofs, btot);
    scanB_kernel<<<1, 64, 0, stream>>>(btot, bbase);
    edge_kernel<<<N_EDGES / 128, 256, 0, stream>>>(E, src, dst, rank, lofs, bbase, wbf,
                                                   b1, b2, Bb, Cb, Vp, msg);
    aggregate_kernel<<<(N_NODES * 64 + 255) / 256, 256, 0, stream>>>(msg, lofs, bbase, cnt, out);
}